// Round 5
// baseline (248.349 us; speedup 1.0000x reference)
//
#include <hip/hip_runtime.h>
#include <hip/hip_bf16.h>

// B=2, L=256, D=128, H=256 fast-weight (TTT-style) forward.
// Exact rewrite: sequential momentum/weight-decay scan -> decay-weighted
// attention with composed decay matrix S = wd_cs @ mom_cs via the stable
// O(L^2) recurrence (all exponents <= 0 in the live region).
//
// v5: single fused kernel, 256 blocks x 256 threads, two software grid
// barriers (device-scope atomics; counters zeroed via hipMemsetAsync).
//   Phase P: blocks 0..143 interleave weights; 144..145 gate/decay scan.
//   Phase T: all 256 blocks, 2 tokens/block: q,k,v,Z1,z1q,X2,gZ1,gZ2.
//   Phase Q: all 256 blocks, 2 tokens/block: score1->Zq1->silu->score2->Zq2.
// Streaming loops are unroll-8 so ~8 loads/wave stay in flight (1 wave/SIMD).

#define Bc 2
#define Lc 256
#define Dc 128
#define Hc 256
#define Tt 2
#define NBLK 256

__device__ __forceinline__ float sigf(float z)  { return 1.f / (1.f + expf(-z)); }
__device__ __forceinline__ float siluf(float z) { return z * sigf(z); }
// replicates reference silu_backward exactly: s + sigmoid(z)*(1-s), s=silu(z)
__device__ __forceinline__ float silubwdf(float z) {
    float sg = sigf(z);
    float s  = z * sg;
    return s + sg * (1.f - s);
}
__device__ __forceinline__ float softplusf(float z) {
    if (z > 20.f)  return z;
    if (z < -20.f) return expf(z);
    return log1pf(expf(z));
}
__device__ __forceinline__ float dot4(float4 a, float4 b) {
    return a.x*b.x + a.y*b.y + a.z*b.z + a.w*b.w;
}

union __align__(16) SMem {
    struct { float lr[Lc], lw[Lc], ewd[Lc], clm[Lc], cwd[Lc]; } scan;
    struct { float xs[Tt][Dc], qs[Tt][Dc], ks[Tt][Dc], X2s[Tt][Hc],
                   pz[2][Tt][Dc], pv[2][Tt][Dc], gZ2s[Tt][Dc]; } tok;
    struct { float qs[Tt][Dc], ss[Tt][Lc], arow[Tt][Lc], xq2s[Tt][Hc],
                   pm[2][Tt][Dc], pw[2][Tt][Dc]; } qry;
};

__device__ __forceinline__ void grid_barrier(unsigned* cnt, unsigned nblk) {
    __syncthreads();
    if (threadIdx.x == 0) {
        __threadfence();   // flush prior writes to device scope
        __hip_atomic_fetch_add(cnt, 1u, __ATOMIC_RELEASE, __HIP_MEMORY_SCOPE_AGENT);
        while (__hip_atomic_load(cnt, __ATOMIC_ACQUIRE, __HIP_MEMORY_SCOPE_AGENT) < nblk)
            __builtin_amdgcn_s_sleep(2);
        __threadfence();   // invalidate caches before reading others' data
    }
    __syncthreads();
}

__global__ __launch_bounds__(256) void k_fused(
    const float* __restrict__ x,
    const float* __restrict__ W1, const float* __restrict__ b1v,
    const float* __restrict__ W2, const float* __restrict__ b2v,
    const float* __restrict__ Wq, const float* __restrict__ bq,
    const float* __restrict__ Wk, const float* __restrict__ bk,
    const float* __restrict__ Wv, const float* __restrict__ bv,
    const float* __restrict__ Wlr, const float* __restrict__ blr,
    const float* __restrict__ Wm,  const float* __restrict__ bm,
    const float* __restrict__ Wwd, const float* __restrict__ bwd,
    float* __restrict__ qo, float* __restrict__ KT, float* __restrict__ X2T,
    float* __restrict__ GZ1, float* __restrict__ GZ2, float* __restrict__ z1q,
    float* __restrict__ Ssc, float* __restrict__ wdf,
    float4* __restrict__ Wq4, float4* __restrict__ Wk4, float4* __restrict__ Wv4,
    float4* __restrict__ W14, float4* __restrict__ W2q4, float4* __restrict__ W2c4,
    unsigned* __restrict__ cnt,
    float* __restrict__ out)
{
    __shared__ SMem sm;
    const int bb  = blockIdx.x;
    const int tid = threadIdx.x;

    // ================= Phase P =================
    if (bb < 144) {
        if (bb < 112) {
            const float* in; float4* o; int M, N, base;
            if      (bb < 16) { in = Wq; o = Wq4;  M = 128; N = 128; base = 0;  }
            else if (bb < 32) { in = Wk; o = Wk4;  M = 128; N = 128; base = 16; }
            else if (bb < 48) { in = Wv; o = Wv4;  M = 128; N = 128; base = 32; }
            else if (bb < 80) { in = W1; o = W14;  M = 256; N = 128; base = 48; }
            else              { in = W2; o = W2q4; M = 128; N = 256; base = 80; }
            const int idx = (bb - base) * 256 + tid;
            const int r = idx % M, g = idx / M;
            o[idx] = *(const float4*)(in + r * N + 4 * g);
        } else {
            const int idx = (bb - 112) * 256 + tid;      // 0..8191
            const int c = idx & 255, g = idx >> 8;
            W2c4[idx] = make_float4(W2[(4*g+0)*Hc + c], W2[(4*g+1)*Hc + c],
                                    W2[(4*g+2)*Hc + c], W2[(4*g+3)*Hc + c]);
        }
    } else if (bb < 146) {
        // ---- gate scan: 1 block per batch ----
        const int b = bb - 144;
        const int l = tid;
        const float4* xr4 = (const float4*)(x + (b * Lc + l) * Dc);
        const float4* wl4 = (const float4*)Wlr;
        const float4* wm4 = (const float4*)Wm;
        const float4* ww4 = (const float4*)Wwd;
        float dlr = blr[0], dm = bm[0], dw = bwd[0];
        #pragma unroll 4
        for (int j = 0; j < Dc / 4; ++j) {
            float4 xv = xr4[j];
            dlr += dot4(wl4[j], xv);
            dm  += dot4(wm4[j], xv);
            dw  += dot4(ww4[j], xv);
        }
        sm.scan.lr[l] = softplusf(dlr);
        float lm = -softplusf(-dm);   // log sigmoid
        float lw = -softplusf(-dw);
        sm.scan.lw[l]  = lw;
        sm.scan.clm[l] = lm;
        sm.scan.cwd[l] = lw;
        __syncthreads();
        for (int off = 1; off < Lc; off <<= 1) {
            float a = (l >= off) ? sm.scan.clm[l - off] : 0.f;
            float c = (l >= off) ? sm.scan.cwd[l - off] : 0.f;
            __syncthreads();
            sm.scan.clm[l] += a; sm.scan.cwd[l] += c;
            __syncthreads();
        }
        wdf[b * Lc + l] = expf(sm.scan.cwd[l]);
        sm.scan.ewd[l] = __expf(sm.scan.lw[l]);
        __syncthreads();
        const int   m     = l;
        const float clm_m = sm.scan.clm[m];
        const float lrm   = sm.scan.lr[m];
        float* outp = Ssc + (b * Lc) * Lc + m;
        float s = 0.f;
        for (int ll = 0; ll < Lc; ++ll) {
            float e2 = __expf(sm.scan.clm[ll] - clm_m);
            s = (ll >= m) ? (sm.scan.ewd[ll] * s + e2) : 0.f;
            outp[ll * Lc] = s * lrm;
        }
    }

    grid_barrier(&cnt[0], NBLK);

    // ================= Phase T (2 tokens/block) =================
    const int t0 = bb * Tt;
    const int b  = t0 >> 8;
    const int l0 = t0 & 255;

    if (tid < Tt * Dc / 4)
        ((float4*)&sm.tok.xs[0][0])[tid] = ((const float4*)(x + t0 * Dc))[tid];
    __syncthreads();

    // --- phase 1: q (hf=0) | k (hf=1); v split across halves ---
    {
        const int hf = tid >> 7, c = tid & 127;
        const float4* Wmain = hf ? Wk4 : Wq4;
        const float*  bmain = hf ? bk  : bq;
        float a0 = bmain[c], a1 = a0, av0 = 0.f, av1 = 0.f;
        #pragma unroll 8
        for (int j4 = 0; j4 < 32; ++j4) {
            float4 w = Wmain[j4 * Dc + c];
            a0 += dot4(w, *(const float4*)&sm.tok.xs[0][4*j4]);
            a1 += dot4(w, *(const float4*)&sm.tok.xs[1][4*j4]);
        }
        const int v0 = hf * 16;
        #pragma unroll 8
        for (int j4 = v0; j4 < v0 + 16; ++j4) {
            float4 w = Wv4[j4 * Dc + c];
            av0 += dot4(w, *(const float4*)&sm.tok.xs[0][4*j4]);
            av1 += dot4(w, *(const float4*)&sm.tok.xs[1][4*j4]);
        }
        sm.tok.pv[hf][0][c] = av0; sm.tok.pv[hf][1][c] = av1;
        if (hf == 0) {
            sm.tok.qs[0][c] = a0; sm.tok.qs[1][c] = a1;
            qo[(t0 + 0) * Dc + c] = a0;
            qo[(t0 + 1) * Dc + c] = a1;
        } else {
            sm.tok.ks[0][c] = a0; sm.tok.ks[1][c] = a1;
            float* ktp = KT + (size_t)b * 32768;
            ktp[(((c >> 2) * Lc) + l0 + 0) * 4 + (c & 3)] = a0;
            ktp[(((c >> 2) * Lc) + l0 + 1) * 4 + (c & 3)] = a1;
        }
    }
    __syncthreads();

    // --- phase 2: Z1 (from k) and z1q (from q); X2 = silu(Z1) ---
    float z1r0, z1r1;
    {
        const int h = tid;
        const float bb1 = b1v[h];
        float a0 = bb1, a1 = bb1, aq0 = bb1, aq1 = bb1;
        #pragma unroll 8
        for (int d4 = 0; d4 < 32; ++d4) {
            float4 w = W14[d4 * Hc + h];
            a0  += dot4(w, *(const float4*)&sm.tok.ks[0][4*d4]);
            a1  += dot4(w, *(const float4*)&sm.tok.ks[1][4*d4]);
            aq0 += dot4(w, *(const float4*)&sm.tok.qs[0][4*d4]);
            aq1 += dot4(w, *(const float4*)&sm.tok.qs[1][4*d4]);
        }
        z1r0 = a0; z1r1 = a1;
        float s0 = siluf(a0), s1 = siluf(a1);
        sm.tok.X2s[0][h] = s0; sm.tok.X2s[1][h] = s1;
        z1q[(t0 + 0) * Hc + h] = aq0;
        z1q[(t0 + 1) * Hc + h] = aq1;
        float* xtp = X2T + (size_t)b * 65536;
        xtp[(((h >> 2) * Lc) + l0 + 0) * 4 + (h & 3)] = s0;
        xtp[(((h >> 2) * Lc) + l0 + 1) * 4 + (h & 3)] = s1;
    }
    __syncthreads();

    // --- phase 3: Z2 halves; gZ2 = Z2 - v ---
    {
        const int d = tid & 127, hf = tid >> 7;
        float a0 = 0.f, a1 = 0.f;
        const int h0 = hf * 32;
        #pragma unroll 8
        for (int h4 = h0; h4 < h0 + 32; ++h4) {
            float4 w = W2q4[h4 * Dc + d];
            a0 += dot4(w, *(const float4*)&sm.tok.X2s[0][4*h4]);
            a1 += dot4(w, *(const float4*)&sm.tok.X2s[1][4*h4]);
        }
        sm.tok.pz[hf][0][d] = a0; sm.tok.pz[hf][1][d] = a1;
    }
    __syncthreads();
    if (tid < Dc) {
        const int d = tid;
        float g0 = sm.tok.pz[0][0][d] + sm.tok.pz[1][0][d] + b2v[d]
                 - (sm.tok.pv[0][0][d] + sm.tok.pv[1][0][d] + bv[d]);
        float g1 = sm.tok.pz[0][1][d] + sm.tok.pz[1][1][d] + b2v[d]
                 - (sm.tok.pv[0][1][d] + sm.tok.pv[1][1][d] + bv[d]);
        sm.tok.gZ2s[0][d] = g0; sm.tok.gZ2s[1][d] = g1;
        float2 gg = make_float2(g0, g1);
        *(float2*)(GZ2 + (size_t)b * 32768 + (((l0 >> 2) * Dc + d) * 4 + (l0 & 3))) = gg;
    }
    __syncthreads();

    // --- phase 4: gX2 via W2 column-groups; gZ1 = gX2 * silu_bwd(Z1) ---
    {
        const int h = tid;
        float a0 = 0.f, a1 = 0.f;
        #pragma unroll 8
        for (int d4 = 0; d4 < 32; ++d4) {
            float4 w = W2c4[d4 * Hc + h];
            a0 += dot4(w, *(const float4*)&sm.tok.gZ2s[0][4*d4]);
            a1 += dot4(w, *(const float4*)&sm.tok.gZ2s[1][4*d4]);
        }
        float2 vv = make_float2(a0 * silubwdf(z1r0), a1 * silubwdf(z1r1));
        *(float2*)(GZ1 + (size_t)b * 65536 + (((l0 >> 2) * Hc + h) * 4 + (l0 & 3))) = vv;
    }

    grid_barrier(&cnt[1], NBLK);

    // ================= Phase Q (2 tokens/block) =================
    if (tid < Tt * Dc / 4)
        ((float4*)&sm.qry.qs[0][0])[tid] = ((const float4*)(qo + t0 * Dc))[tid];
    const float wdf0 = wdf[t0 + 0], wdf1 = wdf[t0 + 1];
    {
        const int m = tid;
        sm.qry.ss[0][m] = Ssc[(t0 + 0) * Lc + m];
        sm.qry.ss[1][m] = Ssc[(t0 + 1) * Lc + m];
    }
    __syncthreads();

    // --- score1 ---
    {
        const int m = tid;
        const float4* ktb = (const float4*)(KT + (size_t)b * 32768);
        float acc0 = 0.f, acc1 = 0.f;
        #pragma unroll 8
        for (int d4 = 0; d4 < 32; ++d4) {
            float4 kv = ktb[d4 * Lc + m];
            acc0 += dot4(kv, *(const float4*)&sm.qry.qs[0][4*d4]);
            acc1 += dot4(kv, *(const float4*)&sm.qry.qs[1][4*d4]);
        }
        sm.qry.arow[0][m] = sm.qry.ss[0][m] * (acc0 + 1.f);
        sm.qry.arow[1][m] = sm.qry.ss[1][m] * (acc1 + 1.f);
    }
    __syncthreads();

    // --- Zq1 + silu ---
    {
        const int h = tid;
        const float4* g = (const float4*)(GZ1 + (size_t)b * 65536);
        float acc0 = 0.f, acc1 = 0.f;
        #pragma unroll 8
        for (int m4 = 0; m4 < 64; ++m4) {
            float4 gv = g[m4 * Hc + h];
            acc0 += dot4(gv, *(const float4*)&sm.qry.arow[0][4*m4]);
            acc1 += dot4(gv, *(const float4*)&sm.qry.arow[1][4*m4]);
        }
        sm.qry.xq2s[0][h] = siluf(acc0 + wdf0 * z1q[(t0 + 0) * Hc + h]);
        sm.qry.xq2s[1][h] = siluf(acc1 + wdf1 * z1q[(t0 + 1) * Hc + h]);
    }
    __syncthreads();

    // --- score2 ---
    {
        const int m = tid;
        const float4* xtb = (const float4*)(X2T + (size_t)b * 65536);
        float acc0 = 0.f, acc1 = 0.f;
        #pragma unroll 8
        for (int h4 = 0; h4 < 64; ++h4) {
            float4 xv = xtb[h4 * Lc + m];
            acc0 += dot4(xv, *(const float4*)&sm.qry.xq2s[0][4*h4]);
            acc1 += dot4(xv, *(const float4*)&sm.qry.xq2s[1][4*h4]);
        }
        __syncthreads();   // Zq1's arow reads complete before overwrite
        sm.qry.arow[0][m] = sm.qry.ss[0][m] * (acc0 + 1.f);
        sm.qry.arow[1][m] = sm.qry.ss[1][m] * (acc1 + 1.f);
    }
    __syncthreads();

    // --- Zq2 halves ---
    {
        const int d = tid & 127, hf = tid >> 7;
        const int c0 = hf * 32;
        float am0 = 0.f, am1 = 0.f, aw0 = 0.f, aw1 = 0.f;
        const float4* g2 = (const float4*)(GZ2 + (size_t)b * 32768);
        #pragma unroll 8
        for (int m4 = c0; m4 < c0 + 32; ++m4) {
            float4 gv = g2[m4 * Dc + d];
            am0 += dot4(gv, *(const float4*)&sm.qry.arow[0][4*m4]);
            am1 += dot4(gv, *(const float4*)&sm.qry.arow[1][4*m4]);
        }
        #pragma unroll 8
        for (int h4 = c0; h4 < c0 + 32; ++h4) {
            float4 w = W2q4[h4 * Dc + d];
            aw0 += dot4(w, *(const float4*)&sm.qry.xq2s[0][4*h4]);
            aw1 += dot4(w, *(const float4*)&sm.qry.xq2s[1][4*h4]);
        }
        sm.qry.pm[hf][0][d] = am0; sm.qry.pm[hf][1][d] = am1;
        sm.qry.pw[hf][0][d] = aw0; sm.qry.pw[hf][1][d] = aw1;
    }
    __syncthreads();
    if (tid < Dc) {
        const int d = tid;
        out[(t0 + 0) * Dc + d] = (sm.qry.pm[0][0][d] + sm.qry.pm[1][0][d])
            + wdf0 * (b2v[d] + sm.qry.pw[0][0][d] + sm.qry.pw[1][0][d]);
        out[(t0 + 1) * Dc + d] = (sm.qry.pm[0][1][d] + sm.qry.pm[1][1][d])
            + wdf1 * (b2v[d] + sm.qry.pw[0][1][d] + sm.qry.pw[1][1][d]);
    }
}

// ---------------------------------------------------------------------------
extern "C" void kernel_launch(void* const* d_in, const int* in_sizes, int n_in,
                              void* d_out, int out_size, void* d_ws, size_t ws_size,
                              hipStream_t stream)
{
    const float* x   = (const float*)d_in[0];
    const float* W1  = (const float*)d_in[1];
    const float* b1  = (const float*)d_in[2];
    const float* W2  = (const float*)d_in[3];
    const float* b2  = (const float*)d_in[4];
    const float* Wq  = (const float*)d_in[5];
    const float* bq  = (const float*)d_in[6];
    const float* Wk  = (const float*)d_in[7];
    const float* bk  = (const float*)d_in[8];
    const float* Wv  = (const float*)d_in[9];
    const float* bv  = (const float*)d_in[10];
    const float* Wlr = (const float*)d_in[11];
    const float* blr = (const float*)d_in[12];
    const float* Wm  = (const float*)d_in[13];
    const float* bm  = (const float*)d_in[14];
    const float* Wwd = (const float*)d_in[15];
    const float* bwd = (const float*)d_in[16];

    float* ws = (float*)d_ws;
    float*  qo   = ws;                       // 65536
    float*  KT   = ws + 65536;               // 65536
    float*  X2T  = ws + 131072;              // 131072
    float*  GZ1  = ws + 262144;              // 131072
    float*  GZ2  = ws + 393216;              // 65536
    float*  z1q  = ws + 458752;              // 131072
    float*  Ssc  = ws + 589824;              // 131072
    float*  wdf  = ws + 720896;              // 512
    float4* Wq4  = (float4*)(ws + 721408);   // 16384 floats
    float4* Wk4  = (float4*)(ws + 737792);
    float4* Wv4  = (float4*)(ws + 754176);
    float4* W14  = (float4*)(ws + 770560);   // 32768
    float4* W2q4 = (float4*)(ws + 803328);   // 32768
    float4* W2c4 = (float4*)(ws + 836096);   // 32768
    unsigned* cnt = (unsigned*)(ws + 868864);
    float*  out  = (float*)d_out;

    hipMemsetAsync(cnt, 0, 2 * sizeof(unsigned), stream);
    k_fused<<<NBLK, 256, 0, stream>>>(x, W1, b1, W2, b2, Wq, bq, Wk, bk, Wv, bv,
                                      Wlr, blr, Wm, bm, Wwd, bwd,
                                      qo, KT, X2T, GZ1, GZ2, z1q, Ssc, wdf,
                                      Wq4, Wk4, Wv4, W14, W2q4, W2c4, cnt, out);
}

// Round 6
// 148.098 us; speedup vs baseline: 1.6769x; 1.6769x over previous
//
#include <hip/hip_runtime.h>
#include <hip/hip_bf16.h>

// B=2, L=256, D=128, H=256 fast-weight (TTT-style) forward.
// Exact rewrite: sequential momentum/weight-decay scan -> decay-weighted
// attention with composed decay matrix S = wd_cs @ mom_cs via the stable
// O(L^2) recurrence (all exponents <= 0 in the live region).
//
// v6: back to 3 kernels (software grid barrier was a 2x regression — XCD
// fence/invalidate cost). Parallelism fixes instead:
//  - Tt=1, 512 blocks, __launch_bounds__(256,2): 2 blocks/CU, 2 waves/SIMD.
//  - explicit 8-deep float4 prefetch batches in every streaming loop.
//  - k_query exploits causality: all m-loops bounded by token index.

#define Bc 2
#define Lc 256
#define Dc 128
#define Hc 256

__device__ __forceinline__ float sigf(float z)  { return 1.f / (1.f + expf(-z)); }
__device__ __forceinline__ float siluf(float z) { return z * sigf(z); }
// replicates reference silu_backward exactly: s + sigmoid(z)*(1-s), s=silu(z)
__device__ __forceinline__ float silubwdf(float z) {
    float sg = sigf(z);
    float s  = z * sg;
    return s + sg * (1.f - s);
}
__device__ __forceinline__ float softplusf(float z) {
    if (z > 20.f)  return z;
    if (z < -20.f) return expf(z);
    return log1pf(expf(z));
}
__device__ __forceinline__ float dot4(float4 a, float4 b) {
    return a.x*b.x + a.y*b.y + a.z*b.z + a.w*b.w;
}

// ---------------------------------------------------------------------------
// K0: blocks 0..143 interleave weights; blocks 144..145 gate/decay scan.
// ---------------------------------------------------------------------------
__global__ __launch_bounds__(256) void k_pre(
    const float* __restrict__ Wq, const float* __restrict__ Wk,
    const float* __restrict__ Wv, const float* __restrict__ W1,
    const float* __restrict__ W2,
    float4* __restrict__ Wq4, float4* __restrict__ Wk4, float4* __restrict__ Wv4,
    float4* __restrict__ W14, float4* __restrict__ W2q4, float4* __restrict__ W2c4,
    const float* __restrict__ x,
    const float* __restrict__ Wlr, const float* __restrict__ blr,
    const float* __restrict__ Wm,  const float* __restrict__ bm,
    const float* __restrict__ Wwd, const float* __restrict__ bwd,
    float* __restrict__ Ssc, float* __restrict__ wdf)
{
    const int bb = blockIdx.x;
    if (bb < 144) {
        if (bb < 112) {
            const float* in; float4* o; int M, N, base;
            if      (bb < 16) { in = Wq; o = Wq4;  M = 128; N = 128; base = 0;  }
            else if (bb < 32) { in = Wk; o = Wk4;  M = 128; N = 128; base = 16; }
            else if (bb < 48) { in = Wv; o = Wv4;  M = 128; N = 128; base = 32; }
            else if (bb < 80) { in = W1; o = W14;  M = 256; N = 128; base = 48; }
            else              { in = W2; o = W2q4; M = 128; N = 256; base = 80; }
            const int idx = (bb - base) * 256 + threadIdx.x;
            const int r = idx % M, g = idx / M;
            o[idx] = *(const float4*)(in + r * N + 4 * g);
        } else {
            const int idx = (bb - 112) * 256 + threadIdx.x;   // 0..8191
            const int c = idx & 255, g = idx >> 8;
            W2c4[idx] = make_float4(W2[(4*g+0)*Hc + c], W2[(4*g+1)*Hc + c],
                                    W2[(4*g+2)*Hc + c], W2[(4*g+3)*Hc + c]);
        }
        return;
    }

    // ---- gate scan: 1 block per batch ----
    __shared__ float lrS[Lc], lwS[Lc], ewdS[Lc], clmS[Lc], cwdS[Lc];
    const int b = bb - 144;
    const int l = threadIdx.x;

    const float4* xr4 = (const float4*)(x + (b * Lc + l) * Dc);
    const float4* wl4 = (const float4*)Wlr;
    const float4* wm4 = (const float4*)Wm;
    const float4* ww4 = (const float4*)Wwd;
    float dlr = blr[0], dm = bm[0], dw = bwd[0];
    #pragma unroll 4
    for (int j = 0; j < Dc / 4; ++j) {
        float4 xv = xr4[j];
        dlr += dot4(wl4[j], xv);
        dm  += dot4(wm4[j], xv);
        dw  += dot4(ww4[j], xv);
    }
    lrS[l] = softplusf(dlr);
    float lm = -softplusf(-dm);   // log sigmoid
    float lw = -softplusf(-dw);
    lwS[l]  = lw;
    clmS[l] = lm;
    cwdS[l] = lw;
    __syncthreads();

    for (int off = 1; off < Lc; off <<= 1) {
        float a = (l >= off) ? clmS[l - off] : 0.f;
        float c = (l >= off) ? cwdS[l - off] : 0.f;
        __syncthreads();
        clmS[l] += a; cwdS[l] += c;
        __syncthreads();
    }
    wdf[b * Lc + l] = expf(cwdS[l]);
    ewdS[l] = __expf(lwS[l]);
    __syncthreads();

    const int   m     = l;
    const float clm_m = clmS[m];
    const float lrm   = lrS[m];
    float* outp = Ssc + (b * Lc) * Lc + m;
    float s = 0.f;
    for (int ll = 0; ll < Lc; ++ll) {
        float e2 = __expf(clmS[ll] - clm_m);
        s = (ll >= m) ? (ewdS[ll] * s + e2) : 0.f;
        outp[ll * Lc] = s * lrm;
    }
}

// ---------------------------------------------------------------------------
// K1: per-token forward + gradients. 512 blocks x 256 threads, 1 token/block.
// ---------------------------------------------------------------------------
__global__ __launch_bounds__(256, 2) void k_token(
    const float* __restrict__ x,
    const float* __restrict__ b1v, const float* __restrict__ b2v,
    const float* __restrict__ bq,  const float* __restrict__ bk,
    const float* __restrict__ bv,
    const float4* __restrict__ Wq4, const float4* __restrict__ Wk4,
    const float4* __restrict__ Wv4, const float4* __restrict__ W14,
    const float4* __restrict__ W2q4, const float4* __restrict__ W2c4,
    float* __restrict__ qo, float* __restrict__ KT, float* __restrict__ X2T,
    float* __restrict__ z1q, float* __restrict__ GZ1, float* __restrict__ GZ2)
{
    __shared__ __align__(16) float xs[Dc], qs[Dc], ks[Dc];
    __shared__ __align__(16) float X2s[Hc], pz[2][Dc], pv[2][Dc], gZ2s[Dc];

    const int t0  = blockIdx.x;
    const int b   = t0 >> 8;
    const int l0  = t0 & 255;
    const int tid = threadIdx.x;

    if (tid < Dc / 4)
        ((float4*)xs)[tid] = ((const float4*)(x + t0 * Dc))[tid];
    __syncthreads();

    // --- phase 1: q (hf=0) | k (hf=1); v split across halves ---
    {
        const int hf = tid >> 7, c = tid & 127;
        const float4* Wmain = hf ? Wk4 : Wq4;
        float a = (hf ? bk : bq)[c], av = 0.f;
        float4 wb[8];
        for (int j4 = 0; j4 < 32; j4 += 8) {
            #pragma unroll
            for (int u = 0; u < 8; ++u) wb[u] = Wmain[(j4+u) * Dc + c];
            #pragma unroll
            for (int u = 0; u < 8; ++u)
                a += dot4(wb[u], *(const float4*)&xs[4*(j4+u)]);
        }
        const int v0 = hf * 16;
        for (int j4 = v0; j4 < v0 + 16; j4 += 8) {
            #pragma unroll
            for (int u = 0; u < 8; ++u) wb[u] = Wv4[(j4+u) * Dc + c];
            #pragma unroll
            for (int u = 0; u < 8; ++u)
                av += dot4(wb[u], *(const float4*)&xs[4*(j4+u)]);
        }
        pv[hf][c] = av;
        if (hf == 0) {
            qs[c] = a;
            qo[t0 * Dc + c] = a;
        } else {
            ks[c] = a;
            KT[(size_t)b * 32768 + ((c >> 2) * Lc + l0) * 4 + (c & 3)] = a;
        }
    }
    __syncthreads();

    // --- phase 2: Z1 (from k) and z1q (from q); X2 = silu(Z1) ---
    float z1r;
    {
        const int h = tid;
        float a = b1v[h], aq = a;
        float4 wb[8];
        for (int d4 = 0; d4 < 32; d4 += 8) {
            #pragma unroll
            for (int u = 0; u < 8; ++u) wb[u] = W14[(d4+u) * Hc + h];
            #pragma unroll
            for (int u = 0; u < 8; ++u) {
                a  += dot4(wb[u], *(const float4*)&ks[4*(d4+u)]);
                aq += dot4(wb[u], *(const float4*)&qs[4*(d4+u)]);
            }
        }
        z1r = a;
        float s = siluf(a);
        X2s[h] = s;
        z1q[t0 * Hc + h] = aq;
        X2T[(size_t)b * 65536 + ((h >> 2) * Lc + l0) * 4 + (h & 3)] = s;
    }
    __syncthreads();

    // --- phase 3: Z2 halves; gZ2 = Z2 - v ---
    {
        const int d = tid & 127, hf = tid >> 7;
        float a = 0.f;
        const int h0 = hf * 32;
        float4 wb[8];
        for (int h4 = h0; h4 < h0 + 32; h4 += 8) {
            #pragma unroll
            for (int u = 0; u < 8; ++u) wb[u] = W2q4[(h4+u) * Dc + d];
            #pragma unroll
            for (int u = 0; u < 8; ++u)
                a += dot4(wb[u], *(const float4*)&X2s[4*(h4+u)]);
        }
        pz[hf][d] = a;
    }
    __syncthreads();
    if (tid < Dc) {
        const int d = tid;
        float g = pz[0][d] + pz[1][d] + b2v[d] - (pv[0][d] + pv[1][d] + bv[d]);
        gZ2s[d] = g;
        GZ2[(size_t)b * 32768 + ((l0 >> 2) * Dc + d) * 4 + (l0 & 3)] = g;
    }
    __syncthreads();

    // --- phase 4: gX2 via W2 column-groups; gZ1 = gX2 * silu_bwd(Z1) ---
    {
        const int h = tid;
        float a = 0.f;
        float4 wb[8];
        for (int d4 = 0; d4 < 32; d4 += 8) {
            #pragma unroll
            for (int u = 0; u < 8; ++u) wb[u] = W2c4[(d4+u) * Hc + h];
            #pragma unroll
            for (int u = 0; u < 8; ++u)
                a += dot4(wb[u], *(const float4*)&gZ2s[4*(d4+u)]);
        }
        GZ1[(size_t)b * 65536 + ((l0 >> 2) * Hc + h) * 4 + (l0 & 3)]
            = a * silubwdf(z1r);
    }
}

// ---------------------------------------------------------------------------
// K2: fused query. 512 blocks x 256 threads, 1 token/block; causal-bounded.
// ---------------------------------------------------------------------------
__global__ __launch_bounds__(256, 2) void k_query(
    const float* __restrict__ qo,  const float* __restrict__ KT,
    const float* __restrict__ X2T, const float* __restrict__ GZ1,
    const float* __restrict__ GZ2, const float* __restrict__ z1q,
    const float* __restrict__ Ssc, const float* __restrict__ wdf,
    const float4* __restrict__ W2q4, const float* __restrict__ b2v,
    float* __restrict__ out)
{
    __shared__ __align__(16) float qs[Dc], ss[Lc], arow[Lc];
    __shared__ __align__(16) float xq2s[Hc], pm[2][Dc], pw[2][Dc];

    const int t0  = blockIdx.x;
    const int b   = t0 >> 8;
    const int l0  = t0 & 255;
    const int tid = threadIdx.x;
    const int M4  = (l0 >> 2) + 1;        // live m4-groups (causal bound)
    const int mPad = M4 * 4;              // live m range, padded to x4

    if (tid < Dc / 4)
        ((float4*)qs)[tid] = ((const float4*)(qo + t0 * Dc))[tid];
    ss[tid] = Ssc[t0 * Lc + tid];         // zero above diagonal
    const float wdf_t = wdf[t0];
    __syncthreads();

    // --- score1: arow[m] = ss[m]*(q.k[m] + 1), m < mPad ---
    if (tid < mPad) {
        const int m = tid;
        const float4* ktb = (const float4*)(KT + (size_t)b * 32768);
        float acc = 0.f;
        float4 wb[8];
        for (int d4 = 0; d4 < 32; d4 += 8) {
            #pragma unroll
            for (int u = 0; u < 8; ++u) wb[u] = ktb[(d4+u) * Lc + m];
            #pragma unroll
            for (int u = 0; u < 8; ++u)
                acc += dot4(wb[u], *(const float4*)&qs[4*(d4+u)]);
        }
        arow[m] = ss[m] * (acc + 1.f);
    }
    __syncthreads();

    // --- Zq1[h] = sum_{m<mPad} arow[m]*gZ1[m,h] + wdf*z1q ; silu ---
    {
        const int h = tid;
        const float4* g = (const float4*)(GZ1 + (size_t)b * 65536);
        const float4* ar4 = (const float4*)arow;
        float acc = 0.f;
        float4 wb[8];
        int m4 = 0;
        for (; m4 + 8 <= M4; m4 += 8) {
            #pragma unroll
            for (int u = 0; u < 8; ++u) wb[u] = g[(m4+u) * Hc + h];
            #pragma unroll
            for (int u = 0; u < 8; ++u) acc += dot4(wb[u], ar4[m4+u]);
        }
        for (; m4 < M4; ++m4) acc += dot4(g[m4 * Hc + h], ar4[m4]);
        xq2s[h] = siluf(acc + wdf_t * z1q[t0 * Hc + h]);
    }
    __syncthreads();

    // --- score2: arow[m] = ss[m]*(Xq2.X2[m] + 1), m < mPad ---
    if (tid < mPad) {
        const int m = tid;
        const float4* xtb = (const float4*)(X2T + (size_t)b * 65536);
        float acc = 0.f;
        float4 wb[8];
        for (int h4 = 0; h4 < 64; h4 += 8) {
            #pragma unroll
            for (int u = 0; u < 8; ++u) wb[u] = xtb[(h4+u) * Lc + m];
            #pragma unroll
            for (int u = 0; u < 8; ++u)
                acc += dot4(wb[u], *(const float4*)&xq2s[4*(h4+u)]);
        }
        arow[m] = ss[m] * (acc + 1.f);
    }
    __syncthreads();

    // --- Zq2 halves: m4 interleaved over [0,M4); weight term split by h ---
    {
        const int d = tid & 127, hf = tid >> 7;
        const float4* g2  = (const float4*)(GZ2 + (size_t)b * 32768);
        const float4* ar4 = (const float4*)arow;
        float am = 0.f, aw = 0.f;
        float4 wb[8];
        int m4 = hf;
        for (; m4 + 14 < M4; m4 += 16) {
            #pragma unroll
            for (int u = 0; u < 8; ++u) wb[u] = g2[(m4 + 2*u) * Dc + d];
            #pragma unroll
            for (int u = 0; u < 8; ++u) am += dot4(wb[u], ar4[m4 + 2*u]);
        }
        for (; m4 < M4; m4 += 2) am += dot4(g2[m4 * Dc + d], ar4[m4]);
        const int c0 = hf * 32;
        for (int h4 = c0; h4 < c0 + 32; h4 += 8) {
            #pragma unroll
            for (int u = 0; u < 8; ++u) wb[u] = W2q4[(h4+u) * Dc + d];
            #pragma unroll
            for (int u = 0; u < 8; ++u)
                aw += dot4(wb[u], *(const float4*)&xq2s[4*(h4+u)]);
        }
        pm[hf][d] = am; pw[hf][d] = aw;
    }
    __syncthreads();
    if (tid < Dc) {
        const int d = tid;
        out[t0 * Dc + d] = (pm[0][d] + pm[1][d])
            + wdf_t * (b2v[d] + pw[0][d] + pw[1][d]);
    }
}

// ---------------------------------------------------------------------------
extern "C" void kernel_launch(void* const* d_in, const int* in_sizes, int n_in,
                              void* d_out, int out_size, void* d_ws, size_t ws_size,
                              hipStream_t stream)
{
    const float* x   = (const float*)d_in[0];
    const float* W1  = (const float*)d_in[1];
    const float* b1  = (const float*)d_in[2];
    const float* W2  = (const float*)d_in[3];
    const float* b2  = (const float*)d_in[4];
    const float* Wq  = (const float*)d_in[5];
    const float* bq  = (const float*)d_in[6];
    const float* Wk  = (const float*)d_in[7];
    const float* bk  = (const float*)d_in[8];
    const float* Wv  = (const float*)d_in[9];
    const float* bv  = (const float*)d_in[10];
    const float* Wlr = (const float*)d_in[11];
    const float* blr = (const float*)d_in[12];
    const float* Wm  = (const float*)d_in[13];
    const float* bm  = (const float*)d_in[14];
    const float* Wwd = (const float*)d_in[15];
    const float* bwd = (const float*)d_in[16];

    float* ws = (float*)d_ws;
    float*  qo   = ws;                       // 65536
    float*  KT   = ws + 65536;               // 65536
    float*  X2T  = ws + 131072;              // 131072
    float*  GZ1  = ws + 262144;              // 131072
    float*  GZ2  = ws + 393216;              // 65536
    float*  z1q  = ws + 458752;              // 131072
    float*  Ssc  = ws + 589824;              // 131072
    float*  wdf  = ws + 720896;              // 512
    float4* Wq4  = (float4*)(ws + 721408);   // 16384 floats
    float4* Wk4  = (float4*)(ws + 737792);
    float4* Wv4  = (float4*)(ws + 754176);
    float4* W14  = (float4*)(ws + 770560);   // 32768
    float4* W2q4 = (float4*)(ws + 803328);   // 32768
    float4* W2c4 = (float4*)(ws + 836096);   // 32768
    float*  out  = (float*)d_out;

    k_pre<<<146, 256, 0, stream>>>(Wq, Wk, Wv, W1, W2,
                                   Wq4, Wk4, Wv4, W14, W2q4, W2c4,
                                   x, Wlr, blr, Wm, bm, Wwd, bwd, Ssc, wdf);
    k_token<<<Bc * Lc, 256, 0, stream>>>(x, b1, b2, bq, bk, bv,
                                         Wq4, Wk4, Wv4, W14, W2q4, W2c4,
                                         qo, KT, X2T, z1q, GZ1, GZ2);
    k_query<<<Bc * Lc, 256, 0, stream>>>(qo, KT, X2T, GZ1, GZ2, z1q,
                                         Ssc, wdf, W2q4, b2, out);
}

// Round 7
// 146.162 us; speedup vs baseline: 1.6991x; 1.0132x over previous
//
#include <hip/hip_runtime.h>
#include <hip/hip_bf16.h>

// B=2, L=256, D=128, H=256 fast-weight (TTT-style) forward.
// Exact rewrite: sequential momentum/weight-decay scan -> decay-weighted
// attention with composed decay matrix S = wd_cs @ mom_cs via the stable
// O(L^2) recurrence (all exponents <= 0 in the live region).
//
// v7: split-dot parallelism. k_token/k_query use 512-thread blocks (8 waves)
// with every dot product split 2-4 ways across threads (LDS partial combine):
// 16 waves/CU, 4 waves/SIMD -- 2x the latency hiding of v6, ~40% shorter
// per-thread load chains. Weights pre-interleaved (k_pre) so every global
// load is a coalesced float4; causal bounds cut k_query's m-loops.

#define Bc 2
#define Lc 256
#define Dc 128
#define Hc 256

__device__ __forceinline__ float sigf(float z)  { return 1.f / (1.f + expf(-z)); }
__device__ __forceinline__ float siluf(float z) { return z * sigf(z); }
// replicates reference silu_backward exactly: s + sigmoid(z)*(1-s), s=silu(z)
__device__ __forceinline__ float silubwdf(float z) {
    float sg = sigf(z);
    float s  = z * sg;
    return s + sg * (1.f - s);
}
__device__ __forceinline__ float softplusf(float z) {
    if (z > 20.f)  return z;
    if (z < -20.f) return expf(z);
    return log1pf(expf(z));
}
__device__ __forceinline__ float dot4(float4 a, float4 b) {
    return a.x*b.x + a.y*b.y + a.z*b.z + a.w*b.w;
}

// ---------------------------------------------------------------------------
// K0: blocks 0..143 interleave weights; blocks 144..145 gate/decay scan.
// ---------------------------------------------------------------------------
__global__ __launch_bounds__(256) void k_pre(
    const float* __restrict__ Wq, const float* __restrict__ Wk,
    const float* __restrict__ Wv, const float* __restrict__ W1,
    const float* __restrict__ W2,
    float4* __restrict__ Wq4, float4* __restrict__ Wk4, float4* __restrict__ Wv4,
    float4* __restrict__ W14, float4* __restrict__ W2q4, float4* __restrict__ W2c4,
    const float* __restrict__ x,
    const float* __restrict__ Wlr, const float* __restrict__ blr,
    const float* __restrict__ Wm,  const float* __restrict__ bm,
    const float* __restrict__ Wwd, const float* __restrict__ bwd,
    float* __restrict__ Ssc, float* __restrict__ wdf)
{
    const int bb = blockIdx.x;
    if (bb < 144) {
        if (bb < 112) {
            const float* in; float4* o; int M, N, base;
            if      (bb < 16) { in = Wq; o = Wq4;  M = 128; N = 128; base = 0;  }
            else if (bb < 32) { in = Wk; o = Wk4;  M = 128; N = 128; base = 16; }
            else if (bb < 48) { in = Wv; o = Wv4;  M = 128; N = 128; base = 32; }
            else if (bb < 80) { in = W1; o = W14;  M = 256; N = 128; base = 48; }
            else              { in = W2; o = W2q4; M = 128; N = 256; base = 80; }
            const int idx = (bb - base) * 256 + threadIdx.x;
            const int r = idx % M, g = idx / M;
            o[idx] = *(const float4*)(in + r * N + 4 * g);
        } else {
            const int idx = (bb - 112) * 256 + threadIdx.x;   // 0..8191
            const int c = idx & 255, g = idx >> 8;
            W2c4[idx] = make_float4(W2[(4*g+0)*Hc + c], W2[(4*g+1)*Hc + c],
                                    W2[(4*g+2)*Hc + c], W2[(4*g+3)*Hc + c]);
        }
        return;
    }

    // ---- gate scan: 1 block per batch ----
    __shared__ float lrS[Lc], lwS[Lc], ewdS[Lc], clmS[Lc], cwdS[Lc];
    const int b = bb - 144;
    const int l = threadIdx.x;

    const float4* xr4 = (const float4*)(x + (b * Lc + l) * Dc);
    const float4* wl4 = (const float4*)Wlr;
    const float4* wm4 = (const float4*)Wm;
    const float4* ww4 = (const float4*)Wwd;
    float dlr = blr[0], dm = bm[0], dw = bwd[0];
    #pragma unroll 4
    for (int j = 0; j < Dc / 4; ++j) {
        float4 xv = xr4[j];
        dlr += dot4(wl4[j], xv);
        dm  += dot4(wm4[j], xv);
        dw  += dot4(ww4[j], xv);
    }
    lrS[l] = softplusf(dlr);
    float lm = -softplusf(-dm);   // log sigmoid
    float lw = -softplusf(-dw);
    lwS[l]  = lw;
    clmS[l] = lm;
    cwdS[l] = lw;
    __syncthreads();

    for (int off = 1; off < Lc; off <<= 1) {
        float a = (l >= off) ? clmS[l - off] : 0.f;
        float c = (l >= off) ? cwdS[l - off] : 0.f;
        __syncthreads();
        clmS[l] += a; cwdS[l] += c;
        __syncthreads();
    }
    wdf[b * Lc + l] = expf(cwdS[l]);
    ewdS[l] = __expf(lwS[l]);
    __syncthreads();

    const int   m     = l;
    const float clm_m = clmS[m];
    const float lrm   = lrS[m];
    float* outp = Ssc + (b * Lc) * Lc + m;
    float s = 0.f;
    for (int ll = 0; ll < Lc; ++ll) {
        float e2 = __expf(clmS[ll] - clm_m);
        s = (ll >= m) ? (ewdS[ll] * s + e2) : 0.f;
        outp[ll * Lc] = s * lrm;           // lanes consecutive in m: coalesced
    }
}

// ---------------------------------------------------------------------------
// K1: per-token forward + gradients. 512 blocks x 512 threads (split dots).
// ---------------------------------------------------------------------------
__global__ __launch_bounds__(512, 4) void k_token(
    const float* __restrict__ x,
    const float* __restrict__ b1v, const float* __restrict__ b2v,
    const float* __restrict__ bq,  const float* __restrict__ bk,
    const float* __restrict__ bv,
    const float4* __restrict__ Wq4, const float4* __restrict__ Wk4,
    const float4* __restrict__ Wv4, const float4* __restrict__ W14,
    const float4* __restrict__ W2q4, const float4* __restrict__ W2c4,
    float* __restrict__ qo, float* __restrict__ KT, float* __restrict__ X2T,
    float* __restrict__ z1q, float* __restrict__ GZ1, float* __restrict__ GZ2)
{
    __shared__ __align__(16) float xs[Dc], qs[Dc], ks[Dc];
    __shared__ __align__(16) float X2s[Hc], z1s[Hc], gZ2s[Dc];
    __shared__ __align__(16) float pv[2][Dc], pz[4][Dc], pg[2][Hc];

    const int t0  = blockIdx.x;
    const int b   = t0 >> 8;
    const int l0  = t0 & 255;
    const int tid = threadIdx.x;

    if (tid < Dc / 4)
        ((float4*)xs)[tid] = ((const float4*)(x + t0 * Dc))[tid];
    __syncthreads();

    // --- phase 1: group0=q, group1=k, groups2/3 = v halves ---
    {
        const int g = tid >> 7, c = tid & 127;
        float4 wb[8];
        if (g < 2) {
            const float4* W = g ? Wk4 : Wq4;
            float a = (g ? bk : bq)[c];
            for (int j4 = 0; j4 < 32; j4 += 8) {
                #pragma unroll
                for (int u = 0; u < 8; ++u) wb[u] = W[(j4+u) * Dc + c];
                #pragma unroll
                for (int u = 0; u < 8; ++u)
                    a += dot4(wb[u], *(const float4*)&xs[4*(j4+u)]);
            }
            if (g == 0) {
                qs[c] = a;
                qo[t0 * Dc + c] = a;
            } else {
                ks[c] = a;
                KT[(size_t)b * 32768 + ((c >> 2) * Lc + l0) * 4 + (c & 3)] = a;
            }
        } else {
            const int half = g - 2;
            const int j0 = half * 16;
            float av = 0.f;
            for (int j4 = j0; j4 < j0 + 16; j4 += 8) {
                #pragma unroll
                for (int u = 0; u < 8; ++u) wb[u] = Wv4[(j4+u) * Dc + c];
                #pragma unroll
                for (int u = 0; u < 8; ++u)
                    av += dot4(wb[u], *(const float4*)&xs[4*(j4+u)]);
            }
            pv[half][c] = av;
        }
    }
    __syncthreads();

    // --- phase 2: 512 parallel dots: which=0 -> Z1 (from k), which=1 -> z1q ---
    {
        const int which = tid >> 8, h = tid & 255;
        const float* src = which ? qs : ks;
        float a = b1v[h];
        float4 wb[8];
        for (int d4 = 0; d4 < 32; d4 += 8) {
            #pragma unroll
            for (int u = 0; u < 8; ++u) wb[u] = W14[(d4+u) * Hc + h];
            #pragma unroll
            for (int u = 0; u < 8; ++u)
                a += dot4(wb[u], *(const float4*)&src[4*(d4+u)]);
        }
        if (which == 0) {
            z1s[h] = a;
            float s = siluf(a);
            X2s[h] = s;
            X2T[(size_t)b * 65536 + ((h >> 2) * Lc + l0) * 4 + (h & 3)] = s;
        } else {
            z1q[t0 * Hc + h] = a;
        }
    }
    __syncthreads();

    // --- phase 3: Z2 4-way split ---
    {
        const int q4g = tid >> 7, d = tid & 127;
        const int h0 = q4g * 16;
        float a = 0.f;
        float4 wb[8];
        for (int h4 = h0; h4 < h0 + 16; h4 += 8) {
            #pragma unroll
            for (int u = 0; u < 8; ++u) wb[u] = W2q4[(h4+u) * Dc + d];
            #pragma unroll
            for (int u = 0; u < 8; ++u)
                a += dot4(wb[u], *(const float4*)&X2s[4*(h4+u)]);
        }
        pz[q4g][d] = a;
    }
    __syncthreads();
    if (tid < Dc) {
        const int d = tid;
        float g = pz[0][d] + pz[1][d] + pz[2][d] + pz[3][d] + b2v[d]
                - (pv[0][d] + pv[1][d] + bv[d]);
        gZ2s[d] = g;
        GZ2[(size_t)b * 32768 + ((l0 >> 2) * Dc + d) * 4 + (l0 & 3)] = g;
    }
    __syncthreads();

    // --- phase 4: gX2 2-way split; gZ1 = gX2 * silu_bwd(Z1) ---
    {
        const int which = tid >> 8, h = tid & 255;
        const int d0 = which * 16;
        float a = 0.f;
        float4 wb[8];
        for (int d4 = d0; d4 < d0 + 16; d4 += 8) {
            #pragma unroll
            for (int u = 0; u < 8; ++u) wb[u] = W2c4[(d4+u) * Hc + h];
            #pragma unroll
            for (int u = 0; u < 8; ++u)
                a += dot4(wb[u], *(const float4*)&gZ2s[4*(d4+u)]);
        }
        pg[which][h] = a;
    }
    __syncthreads();
    if (tid < Hc) {
        const int h = tid;
        GZ1[(size_t)b * 65536 + ((l0 >> 2) * Hc + h) * 4 + (l0 & 3)]
            = (pg[0][h] + pg[1][h]) * silubwdf(z1s[h]);
    }
}

// ---------------------------------------------------------------------------
// K2: fused query. 512 blocks x 512 threads (split dots); causal-bounded.
// ---------------------------------------------------------------------------
__global__ __launch_bounds__(512, 4) void k_query(
    const float* __restrict__ qo,  const float* __restrict__ KT,
    const float* __restrict__ X2T, const float* __restrict__ GZ1,
    const float* __restrict__ GZ2, const float* __restrict__ z1q,
    const float* __restrict__ Ssc, const float* __restrict__ wdf,
    const float4* __restrict__ W2q4, const float* __restrict__ b2v,
    float* __restrict__ out)
{
    __shared__ __align__(16) float qs[Dc], ss[Lc], arow[Lc], xq2s[Hc];
    __shared__ __align__(16) float ps[2][Lc], pq[2][Hc], pm[4][Dc], pw[4][Dc];

    const int t0  = blockIdx.x;
    const int b   = t0 >> 8;
    const int l0  = t0 & 255;
    const int tid = threadIdx.x;
    const int M4  = (l0 >> 2) + 1;        // live m4-groups (causal bound)
    const int mPad = M4 * 4;              // live m range, padded to x4

    if (tid < Dc / 4)
        ((float4*)qs)[tid] = ((const float4*)(qo + t0 * Dc))[tid];
    if (tid < Lc) ss[tid] = Ssc[t0 * Lc + tid];   // zero above diagonal
    const float wdf_t = wdf[t0];
    __syncthreads();

    // --- score1 partials: 2-way split over d ---
    {
        const int which = tid >> 8, m = tid & 255;
        if (m < mPad) {
            const float4* ktb = (const float4*)(KT + (size_t)b * 32768);
            const int d0 = which * 16;
            float acc = 0.f;
            float4 wb[8];
            for (int d4 = d0; d4 < d0 + 16; d4 += 8) {
                #pragma unroll
                for (int u = 0; u < 8; ++u) wb[u] = ktb[(d4+u) * Lc + m];
                #pragma unroll
                for (int u = 0; u < 8; ++u)
                    acc += dot4(wb[u], *(const float4*)&qs[4*(d4+u)]);
            }
            ps[which][m] = acc;
        }
    }
    __syncthreads();
    if (tid < mPad) arow[tid] = ss[tid] * (ps[0][tid] + ps[1][tid] + 1.f);
    __syncthreads();

    // --- Zq1 partials: 2-way strided split over m4 ---
    {
        const int which = tid >> 8, h = tid & 255;
        const float4* g = (const float4*)(GZ1 + (size_t)b * 65536);
        const float4* ar4 = (const float4*)arow;
        float acc = 0.f;
        float4 wb[8];
        int m4 = which;
        for (; m4 + 14 < M4; m4 += 16) {
            #pragma unroll
            for (int u = 0; u < 8; ++u) wb[u] = g[(m4 + 2*u) * Hc + h];
            #pragma unroll
            for (int u = 0; u < 8; ++u) acc += dot4(wb[u], ar4[m4 + 2*u]);
        }
        for (; m4 < M4; m4 += 2) acc += dot4(g[m4 * Hc + h], ar4[m4]);
        pq[which][h] = acc;
    }
    __syncthreads();
    if (tid < Hc)
        xq2s[tid] = siluf(pq[0][tid] + pq[1][tid] + wdf_t * z1q[t0 * Hc + tid]);
    __syncthreads();

    // --- score2 partials: 2-way split over h ---
    {
        const int which = tid >> 8, m = tid & 255;
        if (m < mPad) {
            const float4* xtb = (const float4*)(X2T + (size_t)b * 65536);
            const int h0 = which * 32;
            float acc = 0.f;
            float4 wb[8];
            for (int h4 = h0; h4 < h0 + 32; h4 += 8) {
                #pragma unroll
                for (int u = 0; u < 8; ++u) wb[u] = xtb[(h4+u) * Lc + m];
                #pragma unroll
                for (int u = 0; u < 8; ++u)
                    acc += dot4(wb[u], *(const float4*)&xq2s[4*(h4+u)]);
            }
            ps[which][m] = acc;
        }
    }
    __syncthreads();
    if (tid < mPad) arow[tid] = ss[tid] * (ps[0][tid] + ps[1][tid] + 1.f);
    __syncthreads();

    // --- Zq2: 4-way split (m-part strided over m4, w-part chunked over h) ---
    {
        const int q4g = tid >> 7, d = tid & 127;
        const float4* g2  = (const float4*)(GZ2 + (size_t)b * 32768);
        const float4* ar4 = (const float4*)arow;
        float am = 0.f, aw = 0.f;
        float4 wb[8];
        int m4 = q4g;
        for (; m4 + 28 < M4; m4 += 32) {
            #pragma unroll
            for (int u = 0; u < 8; ++u) wb[u] = g2[(m4 + 4*u) * Dc + d];
            #pragma unroll
            for (int u = 0; u < 8; ++u) am += dot4(wb[u], ar4[m4 + 4*u]);
        }
        for (; m4 < M4; m4 += 4) am += dot4(g2[m4 * Dc + d], ar4[m4]);
        const int h0 = q4g * 16;
        for (int h4 = h0; h4 < h0 + 16; h4 += 8) {
            #pragma unroll
            for (int u = 0; u < 8; ++u) wb[u] = W2q4[(h4+u) * Dc + d];
            #pragma unroll
            for (int u = 0; u < 8; ++u)
                aw += dot4(wb[u], *(const float4*)&xq2s[4*(h4+u)]);
        }
        pm[q4g][d] = am; pw[q4g][d] = aw;
    }
    __syncthreads();
    if (tid < Dc) {
        const int d = tid;
        out[t0 * Dc + d] = (pm[0][d] + pm[1][d] + pm[2][d] + pm[3][d])
            + wdf_t * (b2v[d] + pw[0][d] + pw[1][d] + pw[2][d] + pw[3][d]);
    }
}

// ---------------------------------------------------------------------------
extern "C" void kernel_launch(void* const* d_in, const int* in_sizes, int n_in,
                              void* d_out, int out_size, void* d_ws, size_t ws_size,
                              hipStream_t stream)
{
    const float* x   = (const float*)d_in[0];
    const float* W1  = (const float*)d_in[1];
    const float* b1  = (const float*)d_in[2];
    const float* W2  = (const float*)d_in[3];
    const float* b2  = (const float*)d_in[4];
    const float* Wq  = (const float*)d_in[5];
    const float* bq  = (const float*)d_in[6];
    const float* Wk  = (const float*)d_in[7];
    const float* bk  = (const float*)d_in[8];
    const float* Wv  = (const float*)d_in[9];
    const float* bv  = (const float*)d_in[10];
    const float* Wlr = (const float*)d_in[11];
    const float* blr = (const float*)d_in[12];
    const float* Wm  = (const float*)d_in[13];
    const float* bm  = (const float*)d_in[14];
    const float* Wwd = (const float*)d_in[15];
    const float* bwd = (const float*)d_in[16];

    float* ws = (float*)d_ws;
    float*  qo   = ws;                       // 65536
    float*  KT   = ws + 65536;               // 65536
    float*  X2T  = ws + 131072;              // 131072
    float*  GZ1  = ws + 262144;              // 131072
    float*  GZ2  = ws + 393216;              // 65536
    float*  z1q  = ws + 458752;              // 131072
    float*  Ssc  = ws + 589824;              // 131072
    float*  wdf  = ws + 720896;              // 512
    float4* Wq4  = (float4*)(ws + 721408);   // 16384 floats
    float4* Wk4  = (float4*)(ws + 737792);
    float4* Wv4  = (float4*)(ws + 754176);
    float4* W14  = (float4*)(ws + 770560);   // 32768
    float4* W2q4 = (float4*)(ws + 803328);   // 32768
    float4* W2c4 = (float4*)(ws + 836096);   // 32768
    float*  out  = (float*)d_out;

    k_pre<<<146, 256, 0, stream>>>(Wq, Wk, Wv, W1, W2,
                                   Wq4, Wk4, Wv4, W14, W2q4, W2c4,
                                   x, Wlr, blr, Wm, bm, Wwd, bwd, Ssc, wdf);
    k_token<<<Bc * Lc, 512, 0, stream>>>(x, b1, b2, bq, bk, bv,
                                         Wq4, Wk4, Wv4, W14, W2q4, W2c4,
                                         qo, KT, X2T, z1q, GZ1, GZ2);
    k_query<<<Bc * Lc, 512, 0, stream>>>(qo, KT, X2T, GZ1, GZ2, z1q,
                                         Ssc, wdf, W2q4, b2, out);
}

// Round 8
// 139.206 us; speedup vs baseline: 1.7840x; 1.0500x over previous
//
#include <hip/hip_runtime.h>
#include <hip/hip_bf16.h>

// B=2, L=256, D=128, H=256 fast-weight (TTT-style) forward.
// Exact rewrite: sequential momentum/weight-decay scan -> decay-weighted
// attention with composed decay matrix S = wd_cs @ mom_cs via the stable
// O(L^2) recurrence (all exponents <= 0 in the live region).
//
// v8: Tt=2 tokens per 512-thread block (256 blocks). Every streamed float4
// (weights, KT/X2T/GZ1/GZ2 columns) feeds TWO dot products -> per-token
// global traffic halved vs v7, deeper ILP per load. Split-dot partials
// combine in LDS. k_pre (weight interleave + gate/decay scan) unchanged.

#define Bc 2
#define Lc 256
#define Dc 128
#define Hc 256

__device__ __forceinline__ float sigf(float z)  { return 1.f / (1.f + expf(-z)); }
__device__ __forceinline__ float siluf(float z) { return z * sigf(z); }
// replicates reference silu_backward exactly: s + sigmoid(z)*(1-s), s=silu(z)
__device__ __forceinline__ float silubwdf(float z) {
    float sg = sigf(z);
    float s  = z * sg;
    return s + sg * (1.f - s);
}
__device__ __forceinline__ float softplusf(float z) {
    if (z > 20.f)  return z;
    if (z < -20.f) return expf(z);
    return log1pf(expf(z));
}
__device__ __forceinline__ float dot4(float4 a, float4 b) {
    return a.x*b.x + a.y*b.y + a.z*b.z + a.w*b.w;
}

// ---------------------------------------------------------------------------
// K0: blocks 0..143 interleave weights; blocks 144..145 gate/decay scan.
// ---------------------------------------------------------------------------
__global__ __launch_bounds__(256) void k_pre(
    const float* __restrict__ Wq, const float* __restrict__ Wk,
    const float* __restrict__ Wv, const float* __restrict__ W1,
    const float* __restrict__ W2,
    float4* __restrict__ Wq4, float4* __restrict__ Wk4, float4* __restrict__ Wv4,
    float4* __restrict__ W14, float4* __restrict__ W2q4, float4* __restrict__ W2c4,
    const float* __restrict__ x,
    const float* __restrict__ Wlr, const float* __restrict__ blr,
    const float* __restrict__ Wm,  const float* __restrict__ bm,
    const float* __restrict__ Wwd, const float* __restrict__ bwd,
    float* __restrict__ Ssc, float* __restrict__ wdf)
{
    const int bb = blockIdx.x;
    if (bb < 144) {
        if (bb < 112) {
            const float* in; float4* o; int M, N, base;
            if      (bb < 16) { in = Wq; o = Wq4;  M = 128; N = 128; base = 0;  }
            else if (bb < 32) { in = Wk; o = Wk4;  M = 128; N = 128; base = 16; }
            else if (bb < 48) { in = Wv; o = Wv4;  M = 128; N = 128; base = 32; }
            else if (bb < 80) { in = W1; o = W14;  M = 256; N = 128; base = 48; }
            else              { in = W2; o = W2q4; M = 128; N = 256; base = 80; }
            const int idx = (bb - base) * 256 + threadIdx.x;
            const int r = idx % M, g = idx / M;
            o[idx] = *(const float4*)(in + r * N + 4 * g);
        } else {
            const int idx = (bb - 112) * 256 + threadIdx.x;   // 0..8191
            const int c = idx & 255, g = idx >> 8;
            W2c4[idx] = make_float4(W2[(4*g+0)*Hc + c], W2[(4*g+1)*Hc + c],
                                    W2[(4*g+2)*Hc + c], W2[(4*g+3)*Hc + c]);
        }
        return;
    }

    // ---- gate scan: 1 block per batch ----
    __shared__ float lrS[Lc], lwS[Lc], ewdS[Lc], clmS[Lc], cwdS[Lc];
    const int b = bb - 144;
    const int l = threadIdx.x;

    const float4* xr4 = (const float4*)(x + (b * Lc + l) * Dc);
    const float4* wl4 = (const float4*)Wlr;
    const float4* wm4 = (const float4*)Wm;
    const float4* ww4 = (const float4*)Wwd;
    float dlr = blr[0], dm = bm[0], dw = bwd[0];
    #pragma unroll 4
    for (int j = 0; j < Dc / 4; ++j) {
        float4 xv = xr4[j];
        dlr += dot4(wl4[j], xv);
        dm  += dot4(wm4[j], xv);
        dw  += dot4(ww4[j], xv);
    }
    lrS[l] = softplusf(dlr);
    float lm = -softplusf(-dm);   // log sigmoid
    float lw = -softplusf(-dw);
    lwS[l]  = lw;
    clmS[l] = lm;
    cwdS[l] = lw;
    __syncthreads();

    for (int off = 1; off < Lc; off <<= 1) {
        float a = (l >= off) ? clmS[l - off] : 0.f;
        float c = (l >= off) ? cwdS[l - off] : 0.f;
        __syncthreads();
        clmS[l] += a; cwdS[l] += c;
        __syncthreads();
    }
    wdf[b * Lc + l] = expf(cwdS[l]);
    ewdS[l] = __expf(lwS[l]);
    __syncthreads();

    const int   m     = l;
    const float clm_m = clmS[m];
    const float lrm   = lrS[m];
    float* outp = Ssc + (b * Lc) * Lc + m;
    float s = 0.f;
    for (int ll = 0; ll < Lc; ++ll) {
        float e2 = __expf(clmS[ll] - clm_m);
        s = (ll >= m) ? (ewdS[ll] * s + e2) : 0.f;
        outp[ll * Lc] = s * lrm;           // lanes consecutive in m: coalesced
    }
}

// ---------------------------------------------------------------------------
// K1: token fwd + grads. 256 blocks x 512 threads, 2 tokens/block.
// ---------------------------------------------------------------------------
__global__ __launch_bounds__(512, 4) void k_token(
    const float* __restrict__ x,
    const float* __restrict__ b1v, const float* __restrict__ b2v,
    const float* __restrict__ bq,  const float* __restrict__ bk,
    const float* __restrict__ bv,
    const float4* __restrict__ Wq4, const float4* __restrict__ Wk4,
    const float4* __restrict__ Wv4, const float4* __restrict__ W14,
    const float4* __restrict__ W2q4, const float4* __restrict__ W2c4,
    float* __restrict__ qo, float* __restrict__ KT, float* __restrict__ X2T,
    float* __restrict__ z1q, float* __restrict__ GZ1, float* __restrict__ GZ2)
{
    __shared__ __align__(16) float xs[2][Dc], qs[2][Dc], ks[2][Dc];
    __shared__ __align__(16) float X2s[2][Hc], z1s[2][Hc], gZ2s[2][Dc];
    __shared__ __align__(16) float pv[2][2][Dc], pz[4][2][Dc], pg[2][2][Hc];

    const int t0  = blockIdx.x * 2;
    const int b   = t0 >> 8;
    const int l0  = t0 & 255;
    const int tid = threadIdx.x;

    if (tid < 2 * Dc / 4)
        ((float4*)&xs[0][0])[tid] = ((const float4*)(x + t0 * Dc))[tid];
    __syncthreads();

    // --- phase 1: g0=q, g1=k, g2/g3=v halves; each load feeds both tokens ---
    {
        const int g = tid >> 7, c = tid & 127;
        float4 wb[8];
        if (g < 2) {
            const float4* W = g ? Wk4 : Wq4;
            float a0 = (g ? bk : bq)[c], a1 = a0;
            for (int j4 = 0; j4 < 32; j4 += 8) {
                #pragma unroll
                for (int u = 0; u < 8; ++u) wb[u] = W[(j4+u) * Dc + c];
                #pragma unroll
                for (int u = 0; u < 8; ++u) {
                    a0 += dot4(wb[u], *(const float4*)&xs[0][4*(j4+u)]);
                    a1 += dot4(wb[u], *(const float4*)&xs[1][4*(j4+u)]);
                }
            }
            if (g == 0) {
                qs[0][c] = a0; qs[1][c] = a1;
                qo[t0 * Dc + c] = a0;
                qo[(t0 + 1) * Dc + c] = a1;
            } else {
                ks[0][c] = a0; ks[1][c] = a1;
                float* ktp = KT + (size_t)b * 32768;
                ktp[((c >> 2) * Lc + l0 + 0) * 4 + (c & 3)] = a0;
                ktp[((c >> 2) * Lc + l0 + 1) * 4 + (c & 3)] = a1;
            }
        } else {
            const int half = g - 2, j0 = half * 16;
            float av0 = 0.f, av1 = 0.f;
            for (int j4 = j0; j4 < j0 + 16; j4 += 8) {
                #pragma unroll
                for (int u = 0; u < 8; ++u) wb[u] = Wv4[(j4+u) * Dc + c];
                #pragma unroll
                for (int u = 0; u < 8; ++u) {
                    av0 += dot4(wb[u], *(const float4*)&xs[0][4*(j4+u)]);
                    av1 += dot4(wb[u], *(const float4*)&xs[1][4*(j4+u)]);
                }
            }
            pv[half][0][c] = av0; pv[half][1][c] = av1;
        }
    }
    __syncthreads();

    // --- phase 2: which=0 -> Z1 (from k), which=1 -> z1q (from q) ---
    {
        const int which = tid >> 8, h = tid & 255;
        const float (*src)[Dc] = which ? qs : ks;
        float a0 = b1v[h], a1 = a0;
        float4 wb[8];
        for (int d4 = 0; d4 < 32; d4 += 8) {
            #pragma unroll
            for (int u = 0; u < 8; ++u) wb[u] = W14[(d4+u) * Hc + h];
            #pragma unroll
            for (int u = 0; u < 8; ++u) {
                a0 += dot4(wb[u], *(const float4*)&src[0][4*(d4+u)]);
                a1 += dot4(wb[u], *(const float4*)&src[1][4*(d4+u)]);
            }
        }
        if (which == 0) {
            z1s[0][h] = a0; z1s[1][h] = a1;
            float s0 = siluf(a0), s1 = siluf(a1);
            X2s[0][h] = s0; X2s[1][h] = s1;
            float* xtp = X2T + (size_t)b * 65536;
            xtp[((h >> 2) * Lc + l0 + 0) * 4 + (h & 3)] = s0;
            xtp[((h >> 2) * Lc + l0 + 1) * 4 + (h & 3)] = s1;
        } else {
            z1q[(t0 + 0) * Hc + h] = a0;
            z1q[(t0 + 1) * Hc + h] = a1;
        }
    }
    __syncthreads();

    // --- phase 3: Z2 4-way h-split, both tokens per load ---
    {
        const int q4g = tid >> 7, d = tid & 127;
        const int h0 = q4g * 16;
        float a0 = 0.f, a1 = 0.f;
        float4 wb[8];
        for (int h4 = h0; h4 < h0 + 16; h4 += 8) {
            #pragma unroll
            for (int u = 0; u < 8; ++u) wb[u] = W2q4[(h4+u) * Dc + d];
            #pragma unroll
            for (int u = 0; u < 8; ++u) {
                a0 += dot4(wb[u], *(const float4*)&X2s[0][4*(h4+u)]);
                a1 += dot4(wb[u], *(const float4*)&X2s[1][4*(h4+u)]);
            }
        }
        pz[q4g][0][d] = a0; pz[q4g][1][d] = a1;
    }
    __syncthreads();
    if (tid < 2 * Dc) {
        const int t = tid >> 7, d = tid & 127;
        float g = pz[0][t][d] + pz[1][t][d] + pz[2][t][d] + pz[3][t][d] + b2v[d]
                - (pv[0][t][d] + pv[1][t][d] + bv[d]);
        gZ2s[t][d] = g;
        const int l = l0 + t;
        GZ2[(size_t)b * 32768 + ((l >> 2) * Dc + d) * 4 + (l & 3)] = g;
    }
    __syncthreads();

    // --- phase 4: gX2 2-way d-split; gZ1 = gX2 * silu_bwd(Z1) ---
    {
        const int which = tid >> 8, h = tid & 255;
        const int d0 = which * 16;
        float a0 = 0.f, a1 = 0.f;
        float4 wb[8];
        for (int d4 = d0; d4 < d0 + 16; d4 += 8) {
            #pragma unroll
            for (int u = 0; u < 8; ++u) wb[u] = W2c4[(d4+u) * Hc + h];
            #pragma unroll
            for (int u = 0; u < 8; ++u) {
                a0 += dot4(wb[u], *(const float4*)&gZ2s[0][4*(d4+u)]);
                a1 += dot4(wb[u], *(const float4*)&gZ2s[1][4*(d4+u)]);
            }
        }
        pg[which][0][h] = a0; pg[which][1][h] = a1;
    }
    __syncthreads();
    {
        const int t = tid >> 8, h = tid & 255;
        const int l = l0 + t;
        GZ1[(size_t)b * 65536 + ((l >> 2) * Hc + h) * 4 + (l & 3)]
            = (pg[0][t][h] + pg[1][t][h]) * silubwdf(z1s[t][h]);
    }
}

// ---------------------------------------------------------------------------
// K2: fused query. 256 blocks x 512 threads, 2 tokens/block; causal-bounded.
// ---------------------------------------------------------------------------
__global__ __launch_bounds__(512, 4) void k_query(
    const float* __restrict__ qo,  const float* __restrict__ KT,
    const float* __restrict__ X2T, const float* __restrict__ GZ1,
    const float* __restrict__ GZ2, const float* __restrict__ z1q,
    const float* __restrict__ Ssc, const float* __restrict__ wdf,
    const float4* __restrict__ W2q4, const float* __restrict__ b2v,
    float* __restrict__ out)
{
    __shared__ __align__(16) float qs[2][Dc], ss[2][Lc], arow[2][Lc], xq2s[2][Hc];
    __shared__ __align__(16) float ps[2][2][Lc], pq[2][2][Hc];
    __shared__ __align__(16) float pm[4][2][Dc], pw[4][2][Dc];

    const int t0  = blockIdx.x * 2;
    const int b   = t0 >> 8;
    const int l0  = t0 & 255;
    const int tid = threadIdx.x;
    const int M4  = ((l0 + 1) >> 2) + 1;   // causal bound for the PAIR (exact:
    const int mPad = M4 * 4;               // ss is zero above each row's diag)

    if (tid < 2 * Dc / 4)
        ((float4*)&qs[0][0])[tid] = ((const float4*)(qo + t0 * Dc))[tid];
    if (tid < Lc) {
        ss[0][tid] = Ssc[(t0 + 0) * Lc + tid];
        ss[1][tid] = Ssc[(t0 + 1) * Lc + tid];
    }
    const float wdf0 = wdf[t0 + 0], wdf1 = wdf[t0 + 1];
    __syncthreads();

    // --- score1 partials: 2-way d-split, both tokens per load ---
    {
        const int which = tid >> 8, m = tid & 255;
        if (m < mPad) {
            const float4* ktb = (const float4*)(KT + (size_t)b * 32768);
            const int d0 = which * 16;
            float acc0 = 0.f, acc1 = 0.f;
            float4 wb[8];
            for (int d4 = d0; d4 < d0 + 16; d4 += 8) {
                #pragma unroll
                for (int u = 0; u < 8; ++u) wb[u] = ktb[(d4+u) * Lc + m];
                #pragma unroll
                for (int u = 0; u < 8; ++u) {
                    acc0 += dot4(wb[u], *(const float4*)&qs[0][4*(d4+u)]);
                    acc1 += dot4(wb[u], *(const float4*)&qs[1][4*(d4+u)]);
                }
            }
            ps[which][0][m] = acc0; ps[which][1][m] = acc1;
        }
    }
    __syncthreads();
    {
        const int t = tid >> 8, m = tid & 255;
        if (m < mPad)
            arow[t][m] = ss[t][m] * (ps[0][t][m] + ps[1][t][m] + 1.f);
    }
    __syncthreads();

    // --- Zq1 partials: 2-way strided m4-split, both tokens per load ---
    {
        const int which = tid >> 8, h = tid & 255;
        const float4* g = (const float4*)(GZ1 + (size_t)b * 65536);
        const float4* ar0 = (const float4*)&arow[0][0];
        const float4* ar1 = (const float4*)&arow[1][0];
        float acc0 = 0.f, acc1 = 0.f;
        float4 wb[8];
        int m4 = which;
        for (; m4 + 14 < M4; m4 += 16) {
            #pragma unroll
            for (int u = 0; u < 8; ++u) wb[u] = g[(m4 + 2*u) * Hc + h];
            #pragma unroll
            for (int u = 0; u < 8; ++u) {
                acc0 += dot4(wb[u], ar0[m4 + 2*u]);
                acc1 += dot4(wb[u], ar1[m4 + 2*u]);
            }
        }
        for (; m4 < M4; m4 += 2) {
            float4 gv = g[m4 * Hc + h];
            acc0 += dot4(gv, ar0[m4]);
            acc1 += dot4(gv, ar1[m4]);
        }
        pq[which][0][h] = acc0; pq[which][1][h] = acc1;
    }
    __syncthreads();
    {
        const int t = tid >> 8, h = tid & 255;
        const float w = t ? wdf1 : wdf0;
        xq2s[t][h] = siluf(pq[0][t][h] + pq[1][t][h]
                           + w * z1q[(t0 + t) * Hc + h]);
    }
    __syncthreads();

    // --- score2 partials: 2-way h-split, both tokens per load ---
    {
        const int which = tid >> 8, m = tid & 255;
        if (m < mPad) {
            const float4* xtb = (const float4*)(X2T + (size_t)b * 65536);
            const int h0 = which * 32;
            float acc0 = 0.f, acc1 = 0.f;
            float4 wb[8];
            for (int h4 = h0; h4 < h0 + 32; h4 += 8) {
                #pragma unroll
                for (int u = 0; u < 8; ++u) wb[u] = xtb[(h4+u) * Lc + m];
                #pragma unroll
                for (int u = 0; u < 8; ++u) {
                    acc0 += dot4(wb[u], *(const float4*)&xq2s[0][4*(h4+u)]);
                    acc1 += dot4(wb[u], *(const float4*)&xq2s[1][4*(h4+u)]);
                }
            }
            ps[which][0][m] = acc0; ps[which][1][m] = acc1;
        }
    }
    __syncthreads();
    {
        const int t = tid >> 8, m = tid & 255;
        if (m < mPad)
            arow[t][m] = ss[t][m] * (ps[0][t][m] + ps[1][t][m] + 1.f);
    }
    __syncthreads();

    // --- Zq2: 4-way split (m-part strided m4, w-part chunked h) ---
    {
        const int q4g = tid >> 7, d = tid & 127;
        const float4* g2  = (const float4*)(GZ2 + (size_t)b * 32768);
        const float4* ar0 = (const float4*)&arow[0][0];
        const float4* ar1 = (const float4*)&arow[1][0];
        float am0 = 0.f, am1 = 0.f, aw0 = 0.f, aw1 = 0.f;
        float4 wb[8];
        int m4 = q4g;
        for (; m4 + 28 < M4; m4 += 32) {
            #pragma unroll
            for (int u = 0; u < 8; ++u) wb[u] = g2[(m4 + 4*u) * Dc + d];
            #pragma unroll
            for (int u = 0; u < 8; ++u) {
                am0 += dot4(wb[u], ar0[m4 + 4*u]);
                am1 += dot4(wb[u], ar1[m4 + 4*u]);
            }
        }
        for (; m4 < M4; m4 += 4) {
            float4 gv = g2[m4 * Dc + d];
            am0 += dot4(gv, ar0[m4]);
            am1 += dot4(gv, ar1[m4]);
        }
        const int h0 = q4g * 16;
        for (int h4 = h0; h4 < h0 + 16; h4 += 8) {
            #pragma unroll
            for (int u = 0; u < 8; ++u) wb[u] = W2q4[(h4+u) * Dc + d];
            #pragma unroll
            for (int u = 0; u < 8; ++u) {
                aw0 += dot4(wb[u], *(const float4*)&xq2s[0][4*(h4+u)]);
                aw1 += dot4(wb[u], *(const float4*)&xq2s[1][4*(h4+u)]);
            }
        }
        pm[q4g][0][d] = am0; pm[q4g][1][d] = am1;
        pw[q4g][0][d] = aw0; pw[q4g][1][d] = aw1;
    }
    __syncthreads();
    if (tid < 2 * Dc) {
        const int t = tid >> 7, d = tid & 127;
        const float w = t ? wdf1 : wdf0;
        out[(t0 + t) * Dc + d] =
            (pm[0][t][d] + pm[1][t][d] + pm[2][t][d] + pm[3][t][d])
            + w * (b2v[d] + pw[0][t][d] + pw[1][t][d] + pw[2][t][d] + pw[3][t][d]);
    }
}

// ---------------------------------------------------------------------------
extern "C" void kernel_launch(void* const* d_in, const int* in_sizes, int n_in,
                              void* d_out, int out_size, void* d_ws, size_t ws_size,
                              hipStream_t stream)
{
    const float* x   = (const float*)d_in[0];
    const float* W1  = (const float*)d_in[1];
    const float* b1  = (const float*)d_in[2];
    const float* W2  = (const float*)d_in[3];
    const float* b2  = (const float*)d_in[4];
    const float* Wq  = (const float*)d_in[5];
    const float* bq  = (const float*)d_in[6];
    const float* Wk  = (const float*)d_in[7];
    const float* bk  = (const float*)d_in[8];
    const float* Wv  = (const float*)d_in[9];
    const float* bv  = (const float*)d_in[10];
    const float* Wlr = (const float*)d_in[11];
    const float* blr = (const float*)d_in[12];
    const float* Wm  = (const float*)d_in[13];
    const float* bm  = (const float*)d_in[14];
    const float* Wwd = (const float*)d_in[15];
    const float* bwd = (const float*)d_in[16];

    float* ws = (float*)d_ws;
    float*  qo   = ws;                       // 65536
    float*  KT   = ws + 65536;               // 65536
    float*  X2T  = ws + 131072;              // 131072
    float*  GZ1  = ws + 262144;              // 131072
    float*  GZ2  = ws + 393216;              // 65536
    float*  z1q  = ws + 458752;              // 131072
    float*  Ssc  = ws + 589824;              // 131072
    float*  wdf  = ws + 720896;              // 512
    float4* Wq4  = (float4*)(ws + 721408);   // 16384 floats
    float4* Wk4  = (float4*)(ws + 737792);
    float4* Wv4  = (float4*)(ws + 754176);
    float4* W14  = (float4*)(ws + 770560);   // 32768
    float4* W2q4 = (float4*)(ws + 803328);   // 32768
    float4* W2c4 = (float4*)(ws + 836096);   // 32768
    float*  out  = (float*)d_out;

    k_pre<<<146, 256, 0, stream>>>(Wq, Wk, Wv, W1, W2,
                                   Wq4, Wk4, Wv4, W14, W2q4, W2c4,
                                   x, Wlr, blr, Wm, bm, Wwd, bwd, Ssc, wdf);
    k_token<<<Bc * Lc / 2, 512, 0, stream>>>(x, b1, b2, bq, bk, bv,
                                             Wq4, Wk4, Wv4, W14, W2q4, W2c4,
                                             qo, KT, X2T, z1q, GZ1, GZ2);
    k_query<<<Bc * Lc / 2, 512, 0, stream>>>(qo, KT, X2T, GZ1, GZ2, z1q,
                                             Ssc, wdf, W2q4, b2, out);
}

// Round 9
// 133.595 us; speedup vs baseline: 1.8590x; 1.0420x over previous
//
#include <hip/hip_runtime.h>
#include <hip/hip_bf16.h>

// B=2, L=256, D=128, H=256 fast-weight (TTT-style) forward.
// Exact rewrite: sequential momentum/weight-decay scan -> decay-weighted
// attention with composed decay matrix S = wd_cs @ mom_cs via the stable
// O(L^2) recurrence (all exponents <= 0 in the live region).
//
// v9: wb[16] prefetch batches (16 loads in flight/wave, 64 VGPR) in all hot
// loops; gate/decay scan folded into k_token's grid (blocks 256/257) so
// k_pre is a pure 144-block weight interleave. Tt=2 tokens/block keeps every
// streamed float4 feeding two dot products.

#define Bc 2
#define Lc 256
#define Dc 128
#define Hc 256

__device__ __forceinline__ float sigf(float z)  { return 1.f / (1.f + expf(-z)); }
__device__ __forceinline__ float siluf(float z) { return z * sigf(z); }
// replicates reference silu_backward exactly: s + sigmoid(z)*(1-s), s=silu(z)
__device__ __forceinline__ float silubwdf(float z) {
    float sg = sigf(z);
    float s  = z * sg;
    return s + sg * (1.f - s);
}
__device__ __forceinline__ float softplusf(float z) {
    if (z > 20.f)  return z;
    if (z < -20.f) return expf(z);
    return log1pf(expf(z));
}
__device__ __forceinline__ float dot4(float4 a, float4 b) {
    return a.x*b.x + a.y*b.y + a.z*b.z + a.w*b.w;
}

// ---------------------------------------------------------------------------
// K0: pure weight interleave, 144 blocks x 256 threads.
// ---------------------------------------------------------------------------
__global__ __launch_bounds__(256) void k_pre(
    const float* __restrict__ Wq, const float* __restrict__ Wk,
    const float* __restrict__ Wv, const float* __restrict__ W1,
    const float* __restrict__ W2,
    float4* __restrict__ Wq4, float4* __restrict__ Wk4, float4* __restrict__ Wv4,
    float4* __restrict__ W14, float4* __restrict__ W2q4, float4* __restrict__ W2c4)
{
    const int bb = blockIdx.x;
    if (bb < 112) {
        const float* in; float4* o; int M, N, base;
        if      (bb < 16) { in = Wq; o = Wq4;  M = 128; N = 128; base = 0;  }
        else if (bb < 32) { in = Wk; o = Wk4;  M = 128; N = 128; base = 16; }
        else if (bb < 48) { in = Wv; o = Wv4;  M = 128; N = 128; base = 32; }
        else if (bb < 80) { in = W1; o = W14;  M = 256; N = 128; base = 48; }
        else              { in = W2; o = W2q4; M = 128; N = 256; base = 80; }
        const int idx = (bb - base) * 256 + threadIdx.x;
        const int r = idx % M, g = idx / M;
        o[idx] = *(const float4*)(in + r * N + 4 * g);
    } else {
        const int idx = (bb - 112) * 256 + threadIdx.x;   // 0..8191
        const int c = idx & 255, g = idx >> 8;
        W2c4[idx] = make_float4(W2[(4*g+0)*Hc + c], W2[(4*g+1)*Hc + c],
                                W2[(4*g+2)*Hc + c], W2[(4*g+3)*Hc + c]);
    }
}

// ---------------------------------------------------------------------------
// K1: token fwd + grads (blocks 0..255, 2 tokens/block) +
//     gate/decay scan (blocks 256/257, one per batch).
// ---------------------------------------------------------------------------
__global__ __launch_bounds__(512, 4) void k_token(
    const float* __restrict__ x,
    const float* __restrict__ b1v, const float* __restrict__ b2v,
    const float* __restrict__ bq,  const float* __restrict__ bk,
    const float* __restrict__ bv,
    const float4* __restrict__ Wq4, const float4* __restrict__ Wk4,
    const float4* __restrict__ Wv4, const float4* __restrict__ W14,
    const float4* __restrict__ W2q4, const float4* __restrict__ W2c4,
    const float* __restrict__ Wlr, const float* __restrict__ blr,
    const float* __restrict__ Wm,  const float* __restrict__ bm,
    const float* __restrict__ Wwd, const float* __restrict__ bwd,
    float* __restrict__ qo, float* __restrict__ KT, float* __restrict__ X2T,
    float* __restrict__ z1q, float* __restrict__ GZ1, float* __restrict__ GZ2,
    float* __restrict__ Ssc, float* __restrict__ wdf)
{
    const int bb  = blockIdx.x;
    const int tid = threadIdx.x;

    if (bb >= Bc * Lc / 2) {
        // ================= gate/decay scan (1 block per batch) =============
        __shared__ float lrS[Lc], lwS[Lc], ewdS[Lc], clmS[Lc], cwdS[Lc];
        const int b = bb - Bc * Lc / 2;
        const int l = tid;
        if (l < Lc) {
            const float4* xr4 = (const float4*)(x + (b * Lc + l) * Dc);
            const float4* wl4 = (const float4*)Wlr;
            const float4* wm4 = (const float4*)Wm;
            const float4* ww4 = (const float4*)Wwd;
            float dlr = blr[0], dm = bm[0], dw = bwd[0];
            #pragma unroll 4
            for (int j = 0; j < Dc / 4; ++j) {
                float4 xv = xr4[j];
                dlr += dot4(wl4[j], xv);
                dm  += dot4(wm4[j], xv);
                dw  += dot4(ww4[j], xv);
            }
            lrS[l] = softplusf(dlr);
            float lm = -softplusf(-dm);   // log sigmoid
            float lw = -softplusf(-dw);
            lwS[l]  = lw;
            clmS[l] = lm;
            cwdS[l] = lw;
        }
        __syncthreads();
        for (int off = 1; off < Lc; off <<= 1) {
            float a = 0.f, c = 0.f;
            if (l < Lc && l >= off) { a = clmS[l - off]; c = cwdS[l - off]; }
            __syncthreads();
            if (l < Lc) { clmS[l] += a; cwdS[l] += c; }
            __syncthreads();
        }
        if (l < Lc) {
            wdf[b * Lc + l] = expf(cwdS[l]);
            ewdS[l] = __expf(lwS[l]);
        }
        __syncthreads();
        if (l < Lc) {
            const int   m     = l;
            const float clm_m = clmS[m];
            const float lrm   = lrS[m];
            float* outp = Ssc + (b * Lc) * Lc + m;
            float s = 0.f;
            for (int ll = 0; ll < Lc; ++ll) {
                float e2 = __expf(clmS[ll] - clm_m);
                s = (ll >= m) ? (ewdS[ll] * s + e2) : 0.f;
                outp[ll * Lc] = s * lrm;     // lanes consecutive in m
            }
        }
        return;
    }

    // ================= token work: 2 tokens/block ==========================
    __shared__ __align__(16) float xs[2][Dc], qs[2][Dc], ks[2][Dc];
    __shared__ __align__(16) float X2s[2][Hc], z1s[2][Hc], gZ2s[2][Dc];
    __shared__ __align__(16) float pv[2][2][Dc], pz[4][2][Dc], pg[2][2][Hc];

    const int t0 = bb * 2;
    const int b  = t0 >> 8;
    const int l0 = t0 & 255;

    if (tid < 2 * Dc / 4)
        ((float4*)&xs[0][0])[tid] = ((const float4*)(x + t0 * Dc))[tid];
    __syncthreads();

    // --- phase 1: g0=q, g1=k, g2/g3=v halves; each load feeds both tokens ---
    {
        const int g = tid >> 7, c = tid & 127;
        float4 wb[16];
        if (g < 2) {
            const float4* W = g ? Wk4 : Wq4;
            float a0 = (g ? bk : bq)[c], a1 = a0;
            for (int j4 = 0; j4 < 32; j4 += 16) {
                #pragma unroll
                for (int u = 0; u < 16; ++u) wb[u] = W[(j4+u) * Dc + c];
                #pragma unroll
                for (int u = 0; u < 16; ++u) {
                    a0 += dot4(wb[u], *(const float4*)&xs[0][4*(j4+u)]);
                    a1 += dot4(wb[u], *(const float4*)&xs[1][4*(j4+u)]);
                }
            }
            if (g == 0) {
                qs[0][c] = a0; qs[1][c] = a1;
                qo[t0 * Dc + c] = a0;
                qo[(t0 + 1) * Dc + c] = a1;
            } else {
                ks[0][c] = a0; ks[1][c] = a1;
                float* ktp = KT + (size_t)b * 32768;
                ktp[((c >> 2) * Lc + l0 + 0) * 4 + (c & 3)] = a0;
                ktp[((c >> 2) * Lc + l0 + 1) * 4 + (c & 3)] = a1;
            }
        } else {
            const int half = g - 2, j0 = half * 16;
            float av0 = 0.f, av1 = 0.f;
            #pragma unroll
            for (int u = 0; u < 16; ++u) wb[u] = Wv4[(j0+u) * Dc + c];
            #pragma unroll
            for (int u = 0; u < 16; ++u) {
                av0 += dot4(wb[u], *(const float4*)&xs[0][4*(j0+u)]);
                av1 += dot4(wb[u], *(const float4*)&xs[1][4*(j0+u)]);
            }
            pv[half][0][c] = av0; pv[half][1][c] = av1;
        }
    }
    __syncthreads();

    // --- phase 2: which=0 -> Z1 (from k), which=1 -> z1q (from q) ---
    {
        const int which = tid >> 8, h = tid & 255;
        const float (*src)[Dc] = which ? qs : ks;
        float a0 = b1v[h], a1 = a0;
        float4 wb[16];
        for (int d4 = 0; d4 < 32; d4 += 16) {
            #pragma unroll
            for (int u = 0; u < 16; ++u) wb[u] = W14[(d4+u) * Hc + h];
            #pragma unroll
            for (int u = 0; u < 16; ++u) {
                a0 += dot4(wb[u], *(const float4*)&src[0][4*(d4+u)]);
                a1 += dot4(wb[u], *(const float4*)&src[1][4*(d4+u)]);
            }
        }
        if (which == 0) {
            z1s[0][h] = a0; z1s[1][h] = a1;
            float s0 = siluf(a0), s1 = siluf(a1);
            X2s[0][h] = s0; X2s[1][h] = s1;
            float* xtp = X2T + (size_t)b * 65536;
            xtp[((h >> 2) * Lc + l0 + 0) * 4 + (h & 3)] = s0;
            xtp[((h >> 2) * Lc + l0 + 1) * 4 + (h & 3)] = s1;
        } else {
            z1q[(t0 + 0) * Hc + h] = a0;
            z1q[(t0 + 1) * Hc + h] = a1;
        }
    }
    __syncthreads();

    // --- phase 3: Z2 4-way h-split, both tokens per load ---
    {
        const int q4g = tid >> 7, d = tid & 127;
        const int h0 = q4g * 16;
        float a0 = 0.f, a1 = 0.f;
        float4 wb[16];
        #pragma unroll
        for (int u = 0; u < 16; ++u) wb[u] = W2q4[(h0+u) * Dc + d];
        #pragma unroll
        for (int u = 0; u < 16; ++u) {
            a0 += dot4(wb[u], *(const float4*)&X2s[0][4*(h0+u)]);
            a1 += dot4(wb[u], *(const float4*)&X2s[1][4*(h0+u)]);
        }
        pz[q4g][0][d] = a0; pz[q4g][1][d] = a1;
    }
    __syncthreads();
    if (tid < 2 * Dc) {
        const int t = tid >> 7, d = tid & 127;
        float g = pz[0][t][d] + pz[1][t][d] + pz[2][t][d] + pz[3][t][d] + b2v[d]
                - (pv[0][t][d] + pv[1][t][d] + bv[d]);
        gZ2s[t][d] = g;
        const int l = l0 + t;
        GZ2[(size_t)b * 32768 + ((l >> 2) * Dc + d) * 4 + (l & 3)] = g;
    }
    __syncthreads();

    // --- phase 4: gX2 2-way d-split; gZ1 = gX2 * silu_bwd(Z1) ---
    {
        const int which = tid >> 8, h = tid & 255;
        const int d0 = which * 16;
        float a0 = 0.f, a1 = 0.f;
        float4 wb[16];
        #pragma unroll
        for (int u = 0; u < 16; ++u) wb[u] = W2c4[(d0+u) * Hc + h];
        #pragma unroll
        for (int u = 0; u < 16; ++u) {
            a0 += dot4(wb[u], *(const float4*)&gZ2s[0][4*(d0+u)]);
            a1 += dot4(wb[u], *(const float4*)&gZ2s[1][4*(d0+u)]);
        }
        pg[which][0][h] = a0; pg[which][1][h] = a1;
    }
    __syncthreads();
    {
        const int t = tid >> 8, h = tid & 255;
        const int l = l0 + t;
        GZ1[(size_t)b * 65536 + ((l >> 2) * Hc + h) * 4 + (l & 3)]
            = (pg[0][t][h] + pg[1][t][h]) * silubwdf(z1s[t][h]);
    }
}

// ---------------------------------------------------------------------------
// K2: fused query. 256 blocks x 512 threads, 2 tokens/block; causal-bounded.
// ---------------------------------------------------------------------------
__global__ __launch_bounds__(512, 4) void k_query(
    const float* __restrict__ qo,  const float* __restrict__ KT,
    const float* __restrict__ X2T, const float* __restrict__ GZ1,
    const float* __restrict__ GZ2, const float* __restrict__ z1q,
    const float* __restrict__ Ssc, const float* __restrict__ wdf,
    const float4* __restrict__ W2q4, const float* __restrict__ b2v,
    float* __restrict__ out)
{
    __shared__ __align__(16) float qs[2][Dc], ss[2][Lc], arow[2][Lc], xq2s[2][Hc];
    __shared__ __align__(16) float ps[2][2][Lc], pq[2][2][Hc];
    __shared__ __align__(16) float pm[4][2][Dc], pw[4][2][Dc];

    const int t0  = blockIdx.x * 2;
    const int b   = t0 >> 8;
    const int l0  = t0 & 255;
    const int tid = threadIdx.x;
    const int M4  = ((l0 + 1) >> 2) + 1;   // causal bound for the PAIR (exact:
    const int mPad = M4 * 4;               // ss is zero above each row's diag)

    if (tid < 2 * Dc / 4)
        ((float4*)&qs[0][0])[tid] = ((const float4*)(qo + t0 * Dc))[tid];
    if (tid < Lc) {
        ss[0][tid] = Ssc[(t0 + 0) * Lc + tid];
        ss[1][tid] = Ssc[(t0 + 1) * Lc + tid];
    }
    const float wdf0 = wdf[t0 + 0], wdf1 = wdf[t0 + 1];
    __syncthreads();

    // --- score1 partials: 2-way d-split, both tokens per load ---
    {
        const int which = tid >> 8, m = tid & 255;
        if (m < mPad) {
            const float4* ktb = (const float4*)(KT + (size_t)b * 32768);
            const int d0 = which * 16;
            float acc0 = 0.f, acc1 = 0.f;
            float4 wb[16];
            #pragma unroll
            for (int u = 0; u < 16; ++u) wb[u] = ktb[(d0+u) * Lc + m];
            #pragma unroll
            for (int u = 0; u < 16; ++u) {
                acc0 += dot4(wb[u], *(const float4*)&qs[0][4*(d0+u)]);
                acc1 += dot4(wb[u], *(const float4*)&qs[1][4*(d0+u)]);
            }
            ps[which][0][m] = acc0; ps[which][1][m] = acc1;
        }
    }
    __syncthreads();
    {
        const int t = tid >> 8, m = tid & 255;
        if (m < mPad)
            arow[t][m] = ss[t][m] * (ps[0][t][m] + ps[1][t][m] + 1.f);
    }
    __syncthreads();

    // --- Zq1 partials: 2-way strided m4-split, both tokens per load ---
    {
        const int which = tid >> 8, h = tid & 255;
        const float4* g = (const float4*)(GZ1 + (size_t)b * 65536);
        const float4* ar0 = (const float4*)&arow[0][0];
        const float4* ar1 = (const float4*)&arow[1][0];
        float acc0 = 0.f, acc1 = 0.f;
        float4 wb[16];
        int m4 = which;
        for (; m4 + 30 < M4; m4 += 32) {
            #pragma unroll
            for (int u = 0; u < 16; ++u) wb[u] = g[(m4 + 2*u) * Hc + h];
            #pragma unroll
            for (int u = 0; u < 16; ++u) {
                acc0 += dot4(wb[u], ar0[m4 + 2*u]);
                acc1 += dot4(wb[u], ar1[m4 + 2*u]);
            }
        }
        for (; m4 < M4; m4 += 2) {
            float4 gv = g[m4 * Hc + h];
            acc0 += dot4(gv, ar0[m4]);
            acc1 += dot4(gv, ar1[m4]);
        }
        pq[which][0][h] = acc0; pq[which][1][h] = acc1;
    }
    __syncthreads();
    {
        const int t = tid >> 8, h = tid & 255;
        const float w = t ? wdf1 : wdf0;
        xq2s[t][h] = siluf(pq[0][t][h] + pq[1][t][h]
                           + w * z1q[(t0 + t) * Hc + h]);
    }
    __syncthreads();

    // --- score2 partials: 2-way h-split, both tokens per load ---
    {
        const int which = tid >> 8, m = tid & 255;
        if (m < mPad) {
            const float4* xtb = (const float4*)(X2T + (size_t)b * 65536);
            const int h0 = which * 32;
            float acc0 = 0.f, acc1 = 0.f;
            float4 wb[16];
            for (int h4 = h0; h4 < h0 + 32; h4 += 16) {
                #pragma unroll
                for (int u = 0; u < 16; ++u) wb[u] = xtb[(h4+u) * Lc + m];
                #pragma unroll
                for (int u = 0; u < 16; ++u) {
                    acc0 += dot4(wb[u], *(const float4*)&xq2s[0][4*(h4+u)]);
                    acc1 += dot4(wb[u], *(const float4*)&xq2s[1][4*(h4+u)]);
                }
            }
            ps[which][0][m] = acc0; ps[which][1][m] = acc1;
        }
    }
    __syncthreads();
    {
        const int t = tid >> 8, m = tid & 255;
        if (m < mPad)
            arow[t][m] = ss[t][m] * (ps[0][t][m] + ps[1][t][m] + 1.f);
    }
    __syncthreads();

    // --- Zq2: 4-way split (m-part strided m4, w-part chunked h) ---
    {
        const int q4g = tid >> 7, d = tid & 127;
        const float4* g2  = (const float4*)(GZ2 + (size_t)b * 32768);
        const float4* ar0 = (const float4*)&arow[0][0];
        const float4* ar1 = (const float4*)&arow[1][0];
        float am0 = 0.f, am1 = 0.f, aw0 = 0.f, aw1 = 0.f;
        float4 wb[16];
        int m4 = q4g;
        for (; m4 + 60 < M4; m4 += 64) {
            #pragma unroll
            for (int u = 0; u < 16; ++u) wb[u] = g2[(m4 + 4*u) * Dc + d];
            #pragma unroll
            for (int u = 0; u < 16; ++u) {
                am0 += dot4(wb[u], ar0[m4 + 4*u]);
                am1 += dot4(wb[u], ar1[m4 + 4*u]);
            }
        }
        for (; m4 < M4; m4 += 4) {
            float4 gv = g2[m4 * Dc + d];
            am0 += dot4(gv, ar0[m4]);
            am1 += dot4(gv, ar1[m4]);
        }
        const int h0 = q4g * 16;
        #pragma unroll
        for (int u = 0; u < 16; ++u) wb[u] = W2q4[(h0+u) * Dc + d];
        #pragma unroll
        for (int u = 0; u < 16; ++u) {
            aw0 += dot4(wb[u], *(const float4*)&xq2s[0][4*(h0+u)]);
            aw1 += dot4(wb[u], *(const float4*)&xq2s[1][4*(h0+u)]);
        }
        pm[q4g][0][d] = am0; pm[q4g][1][d] = am1;
        pw[q4g][0][d] = aw0; pw[q4g][1][d] = aw1;
    }
    __syncthreads();
    if (tid < 2 * Dc) {
        const int t = tid >> 7, d = tid & 127;
        const float w = t ? wdf1 : wdf0;
        out[(t0 + t) * Dc + d] =
            (pm[0][t][d] + pm[1][t][d] + pm[2][t][d] + pm[3][t][d])
            + w * (b2v[d] + pw[0][t][d] + pw[1][t][d] + pw[2][t][d] + pw[3][t][d]);
    }
}

// ---------------------------------------------------------------------------
extern "C" void kernel_launch(void* const* d_in, const int* in_sizes, int n_in,
                              void* d_out, int out_size, void* d_ws, size_t ws_size,
                              hipStream_t stream)
{
    const float* x   = (const float*)d_in[0];
    const float* W1  = (const float*)d_in[1];
    const float* b1  = (const float*)d_in[2];
    const float* W2  = (const float*)d_in[3];
    const float* b2  = (const float*)d_in[4];
    const float* Wq  = (const float*)d_in[5];
    const float* bq  = (const float*)d_in[6];
    const float* Wk  = (const float*)d_in[7];
    const float* bk  = (const float*)d_in[8];
    const float* Wv  = (const float*)d_in[9];
    const float* bv  = (const float*)d_in[10];
    const float* Wlr = (const float*)d_in[11];
    const float* blr = (const float*)d_in[12];
    const float* Wm  = (const float*)d_in[13];
    const float* bm  = (const float*)d_in[14];
    const float* Wwd = (const float*)d_in[15];
    const float* bwd = (const float*)d_in[16];

    float* ws = (float*)d_ws;
    float*  qo   = ws;                       // 65536
    float*  KT   = ws + 65536;               // 65536
    float*  X2T  = ws + 131072;              // 131072
    float*  GZ1  = ws + 262144;              // 131072
    float*  GZ2  = ws + 393216;              // 65536
    float*  z1q  = ws + 458752;              // 131072
    float*  Ssc  = ws + 589824;              // 131072
    float*  wdf  = ws + 720896;              // 512
    float4* Wq4  = (float4*)(ws + 721408);   // 16384 floats
    float4* Wk4  = (float4*)(ws + 737792);
    float4* Wv4  = (float4*)(ws + 754176);
    float4* W14  = (float4*)(ws + 770560);   // 32768
    float4* W2q4 = (float4*)(ws + 803328);   // 32768
    float4* W2c4 = (float4*)(ws + 836096);   // 32768
    float*  out  = (float*)d_out;

    k_pre<<<144, 256, 0, stream>>>(Wq, Wk, Wv, W1, W2,
                                   Wq4, Wk4, Wv4, W14, W2q4, W2c4);
    k_token<<<Bc * Lc / 2 + Bc, 512, 0, stream>>>(x, b1, b2, bq, bk, bv,
                                                  Wq4, Wk4, Wv4, W14, W2q4, W2c4,
                                                  Wlr, blr, Wm, bm, Wwd, bwd,
                                                  qo, KT, X2T, z1q, GZ1, GZ2,
                                                  Ssc, wdf);
    k_query<<<Bc * Lc / 2, 512, 0, stream>>>(qo, KT, X2T, GZ1, GZ2, z1q,
                                             Ssc, wdf, W2q4, b2, out);
}